// Round 11
// baseline (2703.238 us; speedup 1.0000x reference)
//
#include <hip/hip_runtime.h>
#include <hip/hip_bf16.h>
#include <stdint.h>

#define T_TOK 8192
#define DIM   2048
#define NEXP  8
#define HDIM  1408
#define SHDIM 2816

typedef __attribute__((ext_vector_type(8))) short bfrag;   // 8 x bf16 (4 VGPR)
typedef __attribute__((ext_vector_type(4))) float f32x4;
typedef __attribute__((ext_vector_type(4))) short s16x4;

__device__ __forceinline__ short f2bf(float f) {
    union { float f; uint32_t u; } v; v.f = f;
    return (short)((v.u + 0x8000u) >> 16);   // round-half-up bf16
}
__device__ __forceinline__ float bf2f(short s) {
    union { uint32_t u; float f; } v; v.u = ((uint32_t)(uint16_t)s) << 16;
    return v.f;
}

__device__ __forceinline__ bfrag cvt8(float4 a, float4 b) {
    bfrag r;
    r[0] = f2bf(a.x); r[1] = f2bf(a.y); r[2] = f2bf(a.z); r[3] = f2bf(a.w);
    r[4] = f2bf(b.x); r[5] = f2bf(b.y); r[6] = f2bf(b.z); r[7] = f2bf(b.w);
    return r;
}

__device__ __forceinline__ void gload16(const void* g, void* l) {
    __builtin_amdgcn_global_load_lds(
        (__attribute__((address_space(1))) void*)(g),
        (__attribute__((address_space(3))) void*)(l), 16, 0, 0);
}

#define MFMA16(a, b, c) __builtin_amdgcn_mfma_f32_16x16x32_bf16((a), (b), (c), 0, 0, 0)

// meta: ints [0..7] counts, [8..15] cursor, [16..24] offsets; floats at +32: s_e[8]

__global__ __launch_bounds__(256) void gate_kernel(
    const float* __restrict__ x, const float* __restrict__ gw,
    __hip_bfloat16* __restrict__ xbf,
    int* __restrict__ sel, int* __restrict__ meta, float* __restrict__ s_e)
{
    __shared__ float g[NEXP * DIM];            // 64 KB
    for (int i = threadIdx.x; i < NEXP * DIM; i += 256) g[i] = gw[i];
    __syncthreads();
    const int wid = threadIdx.x >> 6, lane = threadIdx.x & 63;
    for (int it = 0; it < 8; ++it) {
        const int t = blockIdx.x * 32 + wid * 8 + it;
        float acc[NEXP];
#pragma unroll
        for (int e = 0; e < NEXP; ++e) acc[e] = 0.f;
        const float4* xr = (const float4*)(x + (size_t)t * DIM);
        for (int j = 0; j < DIM / 4; j += 64) {
            float4 xv = xr[j + lane];
            s16x4 xv16 = { f2bf(xv.x), f2bf(xv.y), f2bf(xv.z), f2bf(xv.w) };
            *(s16x4*)&xbf[(size_t)t * DIM + (j + lane) * 4] = xv16;
#pragma unroll
            for (int e = 0; e < NEXP; ++e) {
                float4 gv = *(const float4*)&g[e * DIM + (j + lane) * 4];
                acc[e] += xv.x * gv.x + xv.y * gv.y + xv.z * gv.z + xv.w * gv.w;
            }
        }
#pragma unroll
        for (int e = 0; e < NEXP; ++e)
            for (int o = 32; o; o >>= 1) acc[e] += __shfl_xor(acc[e], o);
        if (lane == 0) {
            int e0 = 0; float v0 = acc[0];
#pragma unroll
            for (int e = 1; e < NEXP; ++e) if (acc[e] > v0) { v0 = acc[e]; e0 = e; }
            int e1 = -1; float v1 = -3.4e38f;
#pragma unroll
            for (int e = 0; e < NEXP; ++e) if (e != e0 && acc[e] > v1) { v1 = acc[e]; e1 = e; }
            float p0 = 1.f / (1.f + __expf(v1 - v0));
            float p1 = 1.f - p0;
            sel[2 * t] = e0; sel[2 * t + 1] = e1;
            atomicAdd(&s_e[e0], p0); atomicAdd(&s_e[e1], p1);
            atomicAdd(&meta[e0], 1); atomicAdd(&meta[e1], 1);
        }
    }
}

__global__ void scan_kernel(int* meta) {
    if (threadIdx.x == 0) {
        int acc = 0;
        for (int e = 0; e < NEXP; ++e) {
            meta[16 + e] = acc;
            meta[8 + e]  = acc;
            acc += meta[e];
        }
        meta[24] = acc;
    }
}

__global__ __launch_bounds__(256) void fill_kernel(
    const int* __restrict__ sel, int* __restrict__ meta,
    int* __restrict__ list, int2* __restrict__ slots)
{
    const int t = blockIdx.x * 256 + threadIdx.x;
    int e0 = sel[2 * t], e1 = sel[2 * t + 1];
    int p0 = atomicAdd(&meta[8 + e0], 1); list[p0] = t;
    int p1 = atomicAdd(&meta[8 + e1], 1); list[p1] = t;
    slots[t] = make_int2(p0, p1);
}

// one fused fp32->bf16 conversion for the 6 weight tensors
#define C1 2883584
#define C2 5767168
#define C3 8650752
#define C4 9371648
#define C5 10092544
#define C6 10813440
__global__ __launch_bounds__(256) void cvt6_kernel(
    const float* __restrict__ s0, const float* __restrict__ s1, const float* __restrict__ s2,
    const float* __restrict__ s3, const float* __restrict__ s4, const float* __restrict__ s5,
    __hip_bfloat16* __restrict__ d0, __hip_bfloat16* __restrict__ d1, __hip_bfloat16* __restrict__ d2,
    __hip_bfloat16* __restrict__ d3, __hip_bfloat16* __restrict__ d4, __hip_bfloat16* __restrict__ d5)
{
    const int stride = gridDim.x * 256;
    for (int i = blockIdx.x * 256 + threadIdx.x; i < C6; i += stride) {
        const float* s; __hip_bfloat16* d; int off;
        if      (i < C1) { s = s0; d = d0; off = i; }
        else if (i < C2) { s = s1; d = d1; off = i - C1; }
        else if (i < C3) { s = s2; d = d2; off = i - C2; }
        else if (i < C4) { s = s3; d = d3; off = i - C3; }
        else if (i < C5) { s = s4; d = d4; off = i - C4; }
        else             { s = s5; d = d5; off = i - C5; }
        const float4* p = (const float4*)(s + (size_t)off * 8);
        float4 a = p[0], b = p[1];
        *(bfrag*)(d + (size_t)off * 8) = cvt8(a, b);
    }
}

// ============ fat-wave GEMMs: 4 waves/block (2x2), 256 threads ============
// Same R3 dbuf 2-barrier K-loop (best measured), but each wave owns a 2x
// larger output tile: LDS read duplication drops to exactly 1x (128 KB/block
// per K-step vs 192 KB at 8 waves), and each wave's 128-MFMA cluster per
// K-step exceeds the block's LDS-engine time -> MFMA becomes the binding pipe.
// LDS layout (verified 0-conflict): row r, slot g: byte = r*128 + ((g^(r&7))<<4)

// fused gate+up: act = silu(X@W1^T) * (X@W3^T). BM=256, BN=128, BK=64.
// Wave tile: 128 rows x 64 cols (x2 matrices). acc = 2*32 f32x4 = 256 VGPR.
template<int N, bool GATHER>
__global__ __launch_bounds__(256, 1) void up_v11(
    const __hip_bfloat16* __restrict__ X,
    const __hip_bfloat16* __restrict__ W1,
    const __hip_bfloat16* __restrict__ W3,
    __hip_bfloat16* __restrict__ act,
    const int* __restrict__ list,
    const int* __restrict__ meta)
{
    constexpr int K = DIM;
    constexpr int NT = K / 64;
    constexpr int nx = N / 128, ny = T_TOK / 256, nz = GATHER ? NEXP : 1;
    constexpr int nwg = nx * ny * nz, cpx = nwg / 8;
    const int bid = (int)blockIdx.x + nx * ((int)blockIdx.y + ny * (int)blockIdx.z);
    const int virt = (bid & 7) * cpx + (bid >> 3);
    const int xi = virt % nx;
    const int rest = virt / nx;
    const int yi = rest % ny;
    const int e = rest / ny;

    int count, base;
    if (GATHER) {
        count = meta[e]; base = meta[16 + e];
        if (yi * 256 >= count) return;
    } else { count = T_TOK; base = 0; }
    const int m0 = yi * 256, n0 = xi * 128;

    __shared__ alignas(16) short As[2][256 * 64];    // 64 KB
    __shared__ alignas(16) short B1s[2][128 * 64];   // 32 KB
    __shared__ alignas(16) short B3s[2][128 * 64];   // 32 KB

    const int tid = threadIdx.x, wid = tid >> 6, lane = tid & 63;
    const int rlo = lane >> 3;               // row within 8-row chunk
    const int swslot = (lane & 7) ^ rlo;     // pre-swizzled source 16B slot

    const __hip_bfloat16* pA[8];
#pragma unroll
    for (int q = 0; q < 8; ++q) {
        int row = (q * 4 + wid) * 8 + rlo;   // 0..255
        int r = m0 + row; if (r > count - 1) r = count - 1;
        int ga = GATHER ? list[base + r] : r;
        pA[q] = X + (size_t)ga * K + swslot * 8;
    }
    const __hip_bfloat16* pB1[4];
    const __hip_bfloat16* pB3[4];
#pragma unroll
    for (int q = 0; q < 4; ++q) {
        int row = (q * 4 + wid) * 8 + rlo;   // 0..127
        pB1[q] = W1 + ((size_t)e * N + n0 + row) * K + swslot * 8;
        pB3[q] = W3 + ((size_t)e * N + n0 + row) * K + swslot * 8;
    }

#define STAGE_UP(T, BUF) do { const int k0_ = (T) * 64;                         \
    _Pragma("unroll") for (int q = 0; q < 8; ++q)                               \
        gload16(pA[q] + k0_, &As[BUF][(q * 4 + wid) * 512]);                    \
    _Pragma("unroll") for (int q = 0; q < 4; ++q) {                             \
        gload16(pB1[q] + k0_, &B1s[BUF][(q * 4 + wid) * 512]);                  \
        gload16(pB3[q] + k0_, &B3s[BUF][(q * 4 + wid) * 512]); } } while (0)

    const int wm = wid >> 1, wn = wid & 1;   // 2x2 wave grid
    const int l15 = lane & 15, lhi = lane >> 4;

    f32x4 accg[8][4], accu[8][4];
#pragma unroll
    for (int i = 0; i < 8; ++i)
#pragma unroll
        for (int j = 0; j < 4; ++j) { accg[i][j] = 0.f; accu[i][j] = 0.f; }

    STAGE_UP(0, 0);
    __syncthreads();                         // drains vmcnt: tile 0 landed
    int cur = 0;
#pragma unroll 1
    for (int t = 0; t < NT; ++t) {
        if (t + 1 < NT) STAGE_UP(t + 1, cur ^ 1);
        __builtin_amdgcn_sched_barrier(0);   // pin stage issue before reads
#pragma unroll
        for (int kk = 0; kk < 2; ++kk) {
            bfrag b1f[4], b3f[4];
            const int c = kk * 4 + lhi;
#pragma unroll
            for (int j = 0; j < 4; ++j) {
                int rb = wn * 64 + j * 16 + l15;
                int off = rb * 128 + ((c ^ (rb & 7)) << 4);
                b1f[j] = *(const bfrag*)((const char*)B1s[cur] + off);
                b3f[j] = *(const bfrag*)((const char*)B3s[cur] + off);
            }
            __builtin_amdgcn_s_setprio(1);
#pragma unroll
            for (int i = 0; i < 8; ++i) {
                int ra = wm * 128 + i * 16 + l15;
                bfrag a = *(const bfrag*)((const char*)As[cur] + ra * 128 + ((c ^ (ra & 7)) << 4));
#pragma unroll
                for (int j = 0; j < 4; ++j) {
                    accg[i][j] = MFMA16(a, b1f[j], accg[i][j]);
                    accu[i][j] = MFMA16(a, b3f[j], accu[i][j]);
                }
            }
            __builtin_amdgcn_s_setprio(0);
        }
        __syncthreads();                     // drain: tile t+1 landed
        cur ^= 1;
    }
#undef STAGE_UP

#pragma unroll
    for (int i = 0; i < 8; ++i)
#pragma unroll
        for (int r = 0; r < 4; ++r) {
            int m = wm * 128 + i * 16 + lhi * 4 + r;
            if (m0 + m < count) {
#pragma unroll
                for (int j = 0; j < 4; ++j) {
                    float gg = accg[i][j][r];
                    float uu = accu[i][j][r];
                    float a = gg / (1.f + __expf(-gg)) * uu;   // silu(g)*u
                    int n = n0 + wn * 64 + j * 16 + l15;
                    act[(size_t)(base + m0 + m) * N + n] = __float2bfloat16(a);
                }
            }
        }
}

// down: y = A @ W2^T. BM=256, BN=256, BK=64. Wave tile 128x128, acc=256 VGPR.
// TO_BF16: store unscaled bf16 rows to yscr (expert; combine applies s_e).
template<int KD, bool TO_BF16>
__global__ __launch_bounds__(256, 1) void down_v11(
    const __hip_bfloat16* __restrict__ A,
    const __hip_bfloat16* __restrict__ W2,
    float* __restrict__ out,
    __hip_bfloat16* __restrict__ yscr,
    const int* __restrict__ meta)
{
    constexpr int N = DIM;
    constexpr int NT = KD / 64;
    constexpr int nx = N / 256, ny = T_TOK / 256, nz = TO_BF16 ? NEXP : 1;
    constexpr int nwg = nx * ny * nz, cpx = nwg / 8;
    const int bid = (int)blockIdx.x + nx * ((int)blockIdx.y + ny * (int)blockIdx.z);
    const int virt = (bid & 7) * cpx + (bid >> 3);
    const int xi = virt % nx;
    const int rest = virt / nx;
    const int yi = rest % ny;
    const int e = rest / ny;

    int count, base;
    if (TO_BF16) {
        count = meta[e]; base = meta[16 + e];
        if (yi * 256 >= count) return;
    } else { count = T_TOK; base = 0; }
    const int m0 = yi * 256, n0 = xi * 256;

    __shared__ alignas(16) short As[2][256 * 64];    // 64 KB
    __shared__ alignas(16) short Bs[2][256 * 64];    // 64 KB

    const int tid = threadIdx.x, wid = tid >> 6, lane = tid & 63;
    const int rlo = lane >> 3;
    const int swslot = (lane & 7) ^ rlo;

    const __hip_bfloat16* pA[8];
    const __hip_bfloat16* pB[8];
#pragma unroll
    for (int q = 0; q < 8; ++q) {
        int row = (q * 4 + wid) * 8 + rlo;   // 0..255
        int r = m0 + row; if (r > count - 1) r = count - 1;
        pA[q] = A  + (size_t)(base + r) * KD + swslot * 8;
        pB[q] = W2 + ((size_t)e * N + n0 + row) * KD + swslot * 8;
    }

#define STAGE_DN(T, BUF) do { const int k0_ = (T) * 64;                         \
    _Pragma("unroll") for (int q = 0; q < 8; ++q) {                             \
        gload16(pA[q] + k0_, &As[BUF][(q * 4 + wid) * 512]);                    \
        gload16(pB[q] + k0_, &Bs[BUF][(q * 4 + wid) * 512]); } } while (0)

    const int wm = wid >> 1, wn = wid & 1;
    const int l15 = lane & 15, lhi = lane >> 4;

    f32x4 acc[8][8];
#pragma unroll
    for (int i = 0; i < 8; ++i)
#pragma unroll
        for (int j = 0; j < 8; ++j) acc[i][j] = 0.f;

    STAGE_DN(0, 0);
    __syncthreads();
    int cur = 0;
#pragma unroll 1
    for (int t = 0; t < NT; ++t) {
        if (t + 1 < NT) STAGE_DN(t + 1, cur ^ 1);
        __builtin_amdgcn_sched_barrier(0);
#pragma unroll
        for (int kk = 0; kk < 2; ++kk) {
            bfrag bf[8];
            const int c = kk * 4 + lhi;
#pragma unroll
            for (int j = 0; j < 8; ++j) {
                int rb = wn * 128 + j * 16 + l15;
                bf[j] = *(const bfrag*)((const char*)Bs[cur] + rb * 128 + ((c ^ (rb & 7)) << 4));
            }
            __builtin_amdgcn_s_setprio(1);
#pragma unroll
            for (int i = 0; i < 8; ++i) {
                int ra = wm * 128 + i * 16 + l15;
                bfrag a = *(const bfrag*)((const char*)As[cur] + ra * 128 + ((c ^ (ra & 7)) << 4));
#pragma unroll
                for (int j = 0; j < 8; ++j)
                    acc[i][j] = MFMA16(a, bf[j], acc[i][j]);
            }
            __builtin_amdgcn_s_setprio(0);
        }
        __syncthreads();
        cur ^= 1;
    }
#undef STAGE_DN

#pragma unroll
    for (int i = 0; i < 8; ++i)
#pragma unroll
        for (int r = 0; r < 4; ++r) {
            int m = wm * 128 + i * 16 + lhi * 4 + r;
            if (m0 + m < count) {
#pragma unroll
                for (int j = 0; j < 8; ++j) {
                    int n = n0 + wn * 128 + j * 16 + l15;
                    if (TO_BF16)
                        yscr[(size_t)(base + m0 + m) * DIM + n] = __float2bfloat16(acc[i][j][r]);
                    else
                        out[(size_t)(m0 + m) * DIM + n] = acc[i][j][r];
                }
            }
        }
}

// out[t] += s_e[e0]*y[slot0] + s_e[e1]*y[slot1]
__global__ __launch_bounds__(256) void combine_kernel(
    float* __restrict__ out, const __hip_bfloat16* __restrict__ yscr,
    const int* __restrict__ sel, const int2* __restrict__ slots,
    const float* __restrict__ s_e)
{
    const int t = blockIdx.x;
    const int d = threadIdx.x * 8;
    const int2 sl = slots[t];
    const float se0 = s_e[sel[2 * t]];
    const float se1 = s_e[sel[2 * t + 1]];
    bfrag y0 = *(const bfrag*)&yscr[(size_t)sl.x * DIM + d];
    bfrag y1 = *(const bfrag*)&yscr[(size_t)sl.y * DIM + d];
    float4* o = (float4*)(out + (size_t)t * DIM + d);
    float4 o0 = o[0], o1 = o[1];
    o0.x += se0 * bf2f(y0[0]) + se1 * bf2f(y1[0]);
    o0.y += se0 * bf2f(y0[1]) + se1 * bf2f(y1[1]);
    o0.z += se0 * bf2f(y0[2]) + se1 * bf2f(y1[2]);
    o0.w += se0 * bf2f(y0[3]) + se1 * bf2f(y1[3]);
    o1.x += se0 * bf2f(y0[4]) + se1 * bf2f(y1[4]);
    o1.y += se0 * bf2f(y0[5]) + se1 * bf2f(y1[5]);
    o1.z += se0 * bf2f(y0[6]) + se1 * bf2f(y1[6]);
    o1.w += se0 * bf2f(y0[7]) + se1 * bf2f(y1[7]);
    o[0] = o0; o[1] = o1;
}

extern "C" void kernel_launch(void* const* d_in, const int* in_sizes, int n_in,
                              void* d_out, int out_size, void* d_ws, size_t ws_size,
                              hipStream_t stream) {
    const float* x   = (const float*)d_in[0];
    const float* gw  = (const float*)d_in[1];
    const float* w1  = (const float*)d_in[2];
    const float* w3  = (const float*)d_in[3];
    const float* w2  = (const float*)d_in[4];
    const float* sw1 = (const float*)d_in[5];
    const float* sw3 = (const float*)d_in[6];
    const float* sw2 = (const float*)d_in[7];
    float* out = (float*)d_out;

    const size_t SZ_X   = (size_t)T_TOK * DIM * 2;            // 32 MB
    const size_t SZ_W   = (size_t)NEXP * HDIM * DIM * 2;      // 46.1 MB each
    const size_t SZ_SW  = (size_t)SHDIM * DIM * 2;            // 11.5 MB each
    const size_t SZ_ACT = (size_t)2 * T_TOK * HDIM * 2;       // 46.1 MB
    const size_t need = SZ_X + 3 * SZ_W + 3 * SZ_SW + SZ_ACT
                      + (size_t)6 * T_TOK * sizeof(int) + 512;
    if (need > ws_size) return;

    char* p = (char*)d_ws;
    __hip_bfloat16* xbf   = (__hip_bfloat16*)p; p += SZ_X;
    __hip_bfloat16* w1bf  = (__hip_bfloat16*)p; p += SZ_W;
    __hip_bfloat16* w3bf  = (__hip_bfloat16*)p; p += SZ_W;
    __hip_bfloat16* w2bf  = (__hip_bfloat16*)p; p += SZ_W;
    __hip_bfloat16* sw1bf = (__hip_bfloat16*)p; p += SZ_SW;
    __hip_bfloat16* sw3bf = (__hip_bfloat16*)p; p += SZ_SW;
    __hip_bfloat16* sw2bf = (__hip_bfloat16*)p; p += SZ_SW;
    __hip_bfloat16* act   = (__hip_bfloat16*)p; p += SZ_ACT;
    int*  list  = (int*)p;  p += (size_t)2 * T_TOK * sizeof(int);
    int*  sel   = (int*)p;  p += (size_t)2 * T_TOK * sizeof(int);
    int2* slots = (int2*)p; p += (size_t)2 * T_TOK * sizeof(int);
    int*  meta  = (int*)p;
    float* s_e  = (float*)(meta + 32);
    // y scratch (16384 x 2048 bf16 = 64 MB) aliases xbf+w1bf (dead after expert-up)
    __hip_bfloat16* yscr = (__hip_bfloat16*)d_ws;

    hipMemsetAsync(meta, 0, 256, stream);
    gate_kernel<<<T_TOK / 32, 256, 0, stream>>>(x, gw, xbf, sel, meta, s_e);
    scan_kernel<<<1, 64, 0, stream>>>(meta);
    fill_kernel<<<T_TOK / 256, 256, 0, stream>>>(sel, meta, list, slots);

    cvt6_kernel<<<2048, 256, 0, stream>>>(w1, w3, w2, sw1, sw3, sw2,
                                          w1bf, w3bf, w2bf, sw1bf, sw3bf, sw2bf);

    // shared expert first (plain f32 stores init out)
    up_v11<SHDIM, false><<<dim3(SHDIM / 128, T_TOK / 256, 1), 256, 0, stream>>>(
        xbf, sw1bf, sw3bf, act, nullptr, meta);
    down_v11<SHDIM, false><<<dim3(DIM / 256, T_TOK / 256, 1), 256, 0, stream>>>(
        act, sw2bf, out, nullptr, meta);
    // sparse experts: act -> y (bf16, unscaled) -> combine with s_e scales
    up_v11<HDIM, true><<<dim3(HDIM / 128, T_TOK / 256, NEXP), 256, 0, stream>>>(
        xbf, w1bf, w3bf, act, list, meta);
    down_v11<HDIM, true><<<dim3(DIM / 256, T_TOK / 256, NEXP), 256, 0, stream>>>(
        act, w2bf, out, yscr, meta);
    combine_kernel<<<T_TOK, 256, 0, stream>>>(out, yscr, sel, slots, s_e);
}

// Round 12
// 1000.422 us; speedup vs baseline: 2.7021x; 2.7021x over previous
//
#include <hip/hip_runtime.h>
#include <hip/hip_bf16.h>
#include <stdint.h>

#define T_TOK 8192
#define DIM   2048
#define NEXP  8
#define HDIM  1408
#define SHDIM 2816

typedef __attribute__((ext_vector_type(8))) short bfrag;   // 8 x bf16 (4 VGPR)
typedef __attribute__((ext_vector_type(4))) float f32x4;
typedef __attribute__((ext_vector_type(4))) short s16x4;

__device__ __forceinline__ short f2bf(float f) {
    union { float f; uint32_t u; } v; v.f = f;
    return (short)((v.u + 0x8000u) >> 16);   // round-half-up bf16
}
__device__ __forceinline__ float bf2f(short s) {
    union { uint32_t u; float f; } v; v.u = ((uint32_t)(uint16_t)s) << 16;
    return v.f;
}

__device__ __forceinline__ bfrag cvt8(float4 a, float4 b) {
    bfrag r;
    r[0] = f2bf(a.x); r[1] = f2bf(a.y); r[2] = f2bf(a.z); r[3] = f2bf(a.w);
    r[4] = f2bf(b.x); r[5] = f2bf(b.y); r[6] = f2bf(b.z); r[7] = f2bf(b.w);
    return r;
}

__device__ __forceinline__ void gload16(const void* g, void* l) {
    __builtin_amdgcn_global_load_lds(
        (__attribute__((address_space(1))) void*)(g),
        (__attribute__((address_space(3))) void*)(l), 16, 0, 0);
}

#define MFMA16(a, b, c) __builtin_amdgcn_mfma_f32_16x16x32_bf16((a), (b), (c), 0, 0, 0)

// meta: ints [0..7] counts, [8..15] cursor, [16..24] offsets; floats at +32: s_e[8]

__global__ __launch_bounds__(256) void gate_kernel(
    const float* __restrict__ x, const float* __restrict__ gw,
    __hip_bfloat16* __restrict__ xbf,
    int* __restrict__ sel, int* __restrict__ meta, float* __restrict__ s_e)
{
    __shared__ float g[NEXP * DIM];            // 64 KB
    for (int i = threadIdx.x; i < NEXP * DIM; i += 256) g[i] = gw[i];
    __syncthreads();
    const int wid = threadIdx.x >> 6, lane = threadIdx.x & 63;
    for (int it = 0; it < 8; ++it) {
        const int t = blockIdx.x * 32 + wid * 8 + it;
        float acc[NEXP];
#pragma unroll
        for (int e = 0; e < NEXP; ++e) acc[e] = 0.f;
        const float4* xr = (const float4*)(x + (size_t)t * DIM);
        for (int j = 0; j < DIM / 4; j += 64) {
            float4 xv = xr[j + lane];
            s16x4 xv16 = { f2bf(xv.x), f2bf(xv.y), f2bf(xv.z), f2bf(xv.w) };
            *(s16x4*)&xbf[(size_t)t * DIM + (j + lane) * 4] = xv16;
#pragma unroll
            for (int e = 0; e < NEXP; ++e) {
                float4 gv = *(const float4*)&g[e * DIM + (j + lane) * 4];
                acc[e] += xv.x * gv.x + xv.y * gv.y + xv.z * gv.z + xv.w * gv.w;
            }
        }
#pragma unroll
        for (int e = 0; e < NEXP; ++e)
            for (int o = 32; o; o >>= 1) acc[e] += __shfl_xor(acc[e], o);
        if (lane == 0) {
            int e0 = 0; float v0 = acc[0];
#pragma unroll
            for (int e = 1; e < NEXP; ++e) if (acc[e] > v0) { v0 = acc[e]; e0 = e; }
            int e1 = -1; float v1 = -3.4e38f;
#pragma unroll
            for (int e = 0; e < NEXP; ++e) if (e != e0 && acc[e] > v1) { v1 = acc[e]; e1 = e; }
            float p0 = 1.f / (1.f + __expf(v1 - v0));
            float p1 = 1.f - p0;
            sel[2 * t] = e0; sel[2 * t + 1] = e1;
            atomicAdd(&s_e[e0], p0); atomicAdd(&s_e[e1], p1);
            atomicAdd(&meta[e0], 1); atomicAdd(&meta[e1], 1);
        }
    }
}

__global__ void scan_kernel(int* meta) {
    if (threadIdx.x == 0) {
        int acc = 0;
        for (int e = 0; e < NEXP; ++e) {
            meta[16 + e] = acc;
            meta[8 + e]  = acc;
            acc += meta[e];
        }
        meta[24] = acc;
    }
}

__global__ __launch_bounds__(256) void fill_kernel(
    const int* __restrict__ sel, int* __restrict__ meta,
    int* __restrict__ list, int2* __restrict__ slots)
{
    const int t = blockIdx.x * 256 + threadIdx.x;
    int e0 = sel[2 * t], e1 = sel[2 * t + 1];
    int p0 = atomicAdd(&meta[8 + e0], 1); list[p0] = t;
    int p1 = atomicAdd(&meta[8 + e1], 1); list[p1] = t;
    slots[t] = make_int2(p0, p1);
}

// one fused fp32->bf16 conversion for the 6 weight tensors
#define C1 2883584
#define C2 5767168
#define C3 8650752
#define C4 9371648
#define C5 10092544
#define C6 10813440
__global__ __launch_bounds__(256) void cvt6_kernel(
    const float* __restrict__ s0, const float* __restrict__ s1, const float* __restrict__ s2,
    const float* __restrict__ s3, const float* __restrict__ s4, const float* __restrict__ s5,
    __hip_bfloat16* __restrict__ d0, __hip_bfloat16* __restrict__ d1, __hip_bfloat16* __restrict__ d2,
    __hip_bfloat16* __restrict__ d3, __hip_bfloat16* __restrict__ d4, __hip_bfloat16* __restrict__ d5)
{
    const int stride = gridDim.x * 256;
    for (int i = blockIdx.x * 256 + threadIdx.x; i < C6; i += stride) {
        const float* s; __hip_bfloat16* d; int off;
        if      (i < C1) { s = s0; d = d0; off = i; }
        else if (i < C2) { s = s1; d = d1; off = i - C1; }
        else if (i < C3) { s = s2; d = d2; off = i - C2; }
        else if (i < C4) { s = s3; d = d3; off = i - C3; }
        else if (i < C5) { s = s4; d = d4; off = i - C4; }
        else             { s = s5; d = d5; off = i - C5; }
        const float4* p = (const float4*)(s + (size_t)off * 8);
        float4 a = p[0], b = p[1];
        *(bfrag*)(d + (size_t)off * 8) = cvt8(a, b);
    }
}

// ============ GEMM cores: R3-dbuf 2-barrier loop (best measured) ============
// 8 waves (2x4), 512 threads, 128 KB LDS (passed in). 0-conflict swizzle:
// row r, slot g: byte = r*128 + ((g^(r&7))<<4); linear gload dest +
// inverse-swizzled global source (rule 21).

// act = silu(X@B1^T) * (X@B3^T) for a 256x128 tile. B1p/B3p pre-offset.
template<int N, bool GATHER>
__device__ __forceinline__ void up_core(
    const __hip_bfloat16* __restrict__ X,
    const __hip_bfloat16* __restrict__ B1p,
    const __hip_bfloat16* __restrict__ B3p,
    __hip_bfloat16* __restrict__ actp,
    const int* __restrict__ list,
    int base, int count, int m0, int n0, short* lds)
{
    constexpr int K = DIM;
    constexpr int NT = K / 64;
    short (*As)[256 * 64]  = (short (*)[256 * 64])lds;            // 64 KB
    short (*B1s)[128 * 64] = (short (*)[128 * 64])(lds + 32768);  // 32 KB
    short (*B3s)[128 * 64] = (short (*)[128 * 64])(lds + 49152);  // 32 KB

    const int tid = threadIdx.x, wid = tid >> 6, lane = tid & 63;
    const int rlo = lane >> 3;
    const int swslot = (lane & 7) ^ rlo;

    const __hip_bfloat16* pA[4];
#pragma unroll
    for (int q = 0; q < 4; ++q) {
        int row = (q * 8 + wid) * 8 + rlo;   // 0..255
        int r = m0 + row; if (r > count - 1) r = count - 1;
        int ga = GATHER ? list[base + r] : r;
        pA[q] = X + (size_t)ga * K + swslot * 8;
    }
    const __hip_bfloat16* pB1[2];
    const __hip_bfloat16* pB3[2];
#pragma unroll
    for (int q = 0; q < 2; ++q) {
        int row = (q * 8 + wid) * 8 + rlo;   // 0..127
        pB1[q] = B1p + (size_t)(n0 + row) * K + swslot * 8;
        pB3[q] = B3p + (size_t)(n0 + row) * K + swslot * 8;
    }

#define STAGE_UP(T, BUF) do { const int k0_ = (T) * 64;                         \
    _Pragma("unroll") for (int q = 0; q < 4; ++q)                               \
        gload16(pA[q] + k0_, &As[BUF][(q * 8 + wid) * 512]);                    \
    _Pragma("unroll") for (int q = 0; q < 2; ++q) {                             \
        gload16(pB1[q] + k0_, &B1s[BUF][(q * 8 + wid) * 512]);                  \
        gload16(pB3[q] + k0_, &B3s[BUF][(q * 8 + wid) * 512]); } } while (0)

    const int wm = wid >> 2, wn = wid & 3;
    const int l15 = lane & 15, lhi = lane >> 4;

    f32x4 accg[8][2], accu[8][2];
#pragma unroll
    for (int i = 0; i < 8; ++i)
#pragma unroll
        for (int j = 0; j < 2; ++j) { accg[i][j] = 0.f; accu[i][j] = 0.f; }

    STAGE_UP(0, 0);
    __syncthreads();
    int cur = 0;
#pragma unroll 1
    for (int t = 0; t < NT; ++t) {
        if (t + 1 < NT) STAGE_UP(t + 1, cur ^ 1);
        __builtin_amdgcn_sched_barrier(0);
        bfrag b1f[2][2], b3f[2][2];
#pragma unroll
        for (int j = 0; j < 2; ++j)
#pragma unroll
            for (int kk = 0; kk < 2; ++kk) {
                int rb = wn * 32 + j * 16 + l15;
                int c = kk * 4 + lhi;
                int off = rb * 128 + ((c ^ (rb & 7)) << 4);
                b1f[j][kk] = *(const bfrag*)((const char*)B1s[cur] + off);
                b3f[j][kk] = *(const bfrag*)((const char*)B3s[cur] + off);
            }
        __builtin_amdgcn_s_setprio(1);
#pragma unroll
        for (int i = 0; i < 8; ++i) {
            int ra = wm * 128 + i * 16 + l15;
            const char* abase = (const char*)As[cur] + ra * 128;
            bfrag a0 = *(const bfrag*)(abase + ((lhi       ^ (ra & 7)) << 4));
            bfrag a1 = *(const bfrag*)(abase + (((4 + lhi) ^ (ra & 7)) << 4));
#pragma unroll
            for (int j = 0; j < 2; ++j) {
                accg[i][j] = MFMA16(a0, b1f[j][0], accg[i][j]);
                accu[i][j] = MFMA16(a0, b3f[j][0], accu[i][j]);
                accg[i][j] = MFMA16(a1, b1f[j][1], accg[i][j]);
                accu[i][j] = MFMA16(a1, b3f[j][1], accu[i][j]);
            }
        }
        __builtin_amdgcn_s_setprio(0);
        __syncthreads();
        cur ^= 1;
    }
#undef STAGE_UP

#pragma unroll
    for (int i = 0; i < 8; ++i)
#pragma unroll
        for (int r = 0; r < 4; ++r) {
            int m = wm * 128 + i * 16 + lhi * 4 + r;
            if (m0 + m < count) {
#pragma unroll
                for (int j = 0; j < 2; ++j) {
                    float gg = accg[i][j][r];
                    float uu = accu[i][j][r];
                    float a = gg / (1.f + __expf(-gg)) * uu;   // silu(g)*u
                    int n = n0 + wn * 32 + j * 16 + l15;
                    actp[(size_t)(base + m0 + m) * N + n] = __float2bfloat16(a);
                }
            }
        }
}

// y = A @ B^T for a 256x256 tile. Bp pre-offset.
template<int KD, bool TO_BF16>
__device__ __forceinline__ void down_core(
    const __hip_bfloat16* __restrict__ Ap,
    const __hip_bfloat16* __restrict__ Bp,
    float* __restrict__ out, __hip_bfloat16* __restrict__ yscr,
    int base, int count, int m0, int n0, short* lds)
{
    constexpr int NT = KD / 64;
    short (*As)[256 * 64] = (short (*)[256 * 64])lds;             // 64 KB
    short (*Bs)[256 * 64] = (short (*)[256 * 64])(lds + 32768);   // 64 KB

    const int tid = threadIdx.x, wid = tid >> 6, lane = tid & 63;
    const int rlo = lane >> 3;
    const int swslot = (lane & 7) ^ rlo;

    const __hip_bfloat16* pA[4];
    const __hip_bfloat16* pB[4];
#pragma unroll
    for (int q = 0; q < 4; ++q) {
        int row = (q * 8 + wid) * 8 + rlo;   // 0..255
        int r = m0 + row; if (r > count - 1) r = count - 1;
        pA[q] = Ap + (size_t)(base + r) * KD + swslot * 8;
        pB[q] = Bp + (size_t)(n0 + row) * KD + swslot * 8;
    }

#define STAGE_DN(T, BUF) do { const int k0_ = (T) * 64;                         \
    _Pragma("unroll") for (int q = 0; q < 4; ++q) {                             \
        gload16(pA[q] + k0_, &As[BUF][(q * 8 + wid) * 512]);                    \
        gload16(pB[q] + k0_, &Bs[BUF][(q * 8 + wid) * 512]); } } while (0)

    const int wm = wid >> 2, wn = wid & 3;
    const int l15 = lane & 15, lhi = lane >> 4;

    f32x4 acc[8][4];
#pragma unroll
    for (int i = 0; i < 8; ++i)
#pragma unroll
        for (int j = 0; j < 4; ++j) acc[i][j] = 0.f;

    STAGE_DN(0, 0);
    __syncthreads();
    int cur = 0;
#pragma unroll 1
    for (int t = 0; t < NT; ++t) {
        if (t + 1 < NT) STAGE_DN(t + 1, cur ^ 1);
        __builtin_amdgcn_sched_barrier(0);
        bfrag bf[4][2];
#pragma unroll
        for (int j = 0; j < 4; ++j)
#pragma unroll
            for (int kk = 0; kk < 2; ++kk) {
                int rb = wn * 64 + j * 16 + l15;
                int c = kk * 4 + lhi;
                bf[j][kk] = *(const bfrag*)((const char*)Bs[cur] + rb * 128 + ((c ^ (rb & 7)) << 4));
            }
        __builtin_amdgcn_s_setprio(1);
#pragma unroll
        for (int i = 0; i < 8; ++i) {
            int ra = wm * 128 + i * 16 + l15;
            const char* abase = (const char*)As[cur] + ra * 128;
            bfrag a0 = *(const bfrag*)(abase + ((lhi       ^ (ra & 7)) << 4));
            bfrag a1 = *(const bfrag*)(abase + (((4 + lhi) ^ (ra & 7)) << 4));
#pragma unroll
            for (int j = 0; j < 4; ++j) {
                acc[i][j] = MFMA16(a0, bf[j][0], acc[i][j]);
                acc[i][j] = MFMA16(a1, bf[j][1], acc[i][j]);
            }
        }
        __builtin_amdgcn_s_setprio(0);
        __syncthreads();
        cur ^= 1;
    }
#undef STAGE_DN

#pragma unroll
    for (int i = 0; i < 8; ++i)
#pragma unroll
        for (int r = 0; r < 4; ++r) {
            int m = wm * 128 + i * 16 + lhi * 4 + r;
            if (m0 + m < count) {
#pragma unroll
                for (int j = 0; j < 4; ++j) {
                    int n = n0 + wn * 64 + j * 16 + l15;
                    if (TO_BF16)
                        yscr[(size_t)(base + m0 + m) * DIM + n] = __float2bfloat16(acc[i][j][r]);
                    else
                        out[(size_t)(m0 + m) * DIM + n] = acc[i][j][r];
                }
            }
        }
}

// ---------------- wrappers ----------------
template<int N, bool GATHER>
__global__ __launch_bounds__(512, 2) void up_k(
    const __hip_bfloat16* __restrict__ X,
    const __hip_bfloat16* __restrict__ W1, const __hip_bfloat16* __restrict__ W3,
    __hip_bfloat16* __restrict__ act,
    const int* __restrict__ list, const int* __restrict__ meta)
{
    constexpr int nx = N / 128, ny = T_TOK / 256, nz = GATHER ? NEXP : 1;
    constexpr int nwg = nx * ny * nz, cpx = nwg / 8;
    const int bid = (int)blockIdx.x + nx * ((int)blockIdx.y + ny * (int)blockIdx.z);
    const int virt = (bid & 7) * cpx + (bid >> 3);
    const int xi = virt % nx, rest = virt / nx, yi = rest % ny, e = rest / ny;
    int count, base;
    if (GATHER) { count = meta[e]; base = meta[16 + e]; if (yi * 256 >= count) return; }
    else { count = T_TOK; base = 0; }
    __shared__ alignas(16) short lds[65536];   // 128 KB
    up_core<N, GATHER>(X, W1 + (size_t)e * N * DIM, W3 + (size_t)e * N * DIM,
                       act, list, base, count, yi * 256, xi * 128, lds);
}

template<int KD, bool TO_BF16>
__global__ __launch_bounds__(512, 2) void down_k(
    const __hip_bfloat16* __restrict__ A, const __hip_bfloat16* __restrict__ W2,
    float* __restrict__ out, __hip_bfloat16* __restrict__ yscr,
    const int* __restrict__ meta)
{
    constexpr int nx = DIM / 256, ny = T_TOK / 256, nz = TO_BF16 ? NEXP : 1;
    constexpr int nwg = nx * ny * nz, cpx = nwg / 8;
    const int bid = (int)blockIdx.x + nx * ((int)blockIdx.y + ny * (int)blockIdx.z);
    const int virt = (bid & 7) * cpx + (bid >> 3);
    const int xi = virt % nx, rest = virt / nx, yi = rest % ny, e = rest / ny;
    int count, base;
    if (TO_BF16) { count = meta[e]; base = meta[16 + e]; if (yi * 256 >= count) return; }
    else { count = T_TOK; base = 0; }
    __shared__ alignas(16) short lds[65536];
    down_core<KD, TO_BF16>(A, W2 + (size_t)e * DIM * KD, out, yscr,
                           base, count, yi * 256, xi * 256, lds);
}

// merged middle dispatch: down-shared (256 blocks) + up-expert (2816 blocks).
// No data dependency between the roles; fills down-shared's half-idle round.
__global__ __launch_bounds__(512, 2) void mid_merged(
    const __hip_bfloat16* __restrict__ act_sh, const __hip_bfloat16* __restrict__ sw2bf,
    float* __restrict__ out,
    const __hip_bfloat16* __restrict__ xbf,
    const __hip_bfloat16* __restrict__ w1bf, const __hip_bfloat16* __restrict__ w3bf,
    __hip_bfloat16* __restrict__ act_ex,
    const int* __restrict__ list, const int* __restrict__ meta)
{
    __shared__ alignas(16) short lds[65536];
    const int bid = (int)blockIdx.x;
    if (bid < 256) {
        constexpr int cpx = 256 / 8;
        const int virt = (bid & 7) * cpx + (bid >> 3);
        const int n0 = (virt & 7) * 256, m0 = (virt >> 3) * 256;
        down_core<SHDIM, false>(act_sh, sw2bf, out, nullptr, 0, T_TOK, m0, n0, lds);
    } else {
        const int b = bid - 256;                 // 256 % 8 == 0: b%8 still = XCD
        constexpr int cpx = 2816 / 8;
        const int virt = (b & 7) * cpx + (b >> 3);
        const int e = virt / 352, r = virt % 352;
        const int n0 = (r % 11) * 128, m0 = (r / 11) * 256;
        const int count = meta[e], base = meta[16 + e];
        if (m0 >= count) return;
        up_core<HDIM, true>(xbf, w1bf + (size_t)e * HDIM * DIM, w3bf + (size_t)e * HDIM * DIM,
                            act_ex, list, base, count, m0, n0, lds);
    }
}

// out[t] += s_e[e0]*y[slot0] + s_e[e1]*y[slot1]
__global__ __launch_bounds__(256) void combine_kernel(
    float* __restrict__ out, const __hip_bfloat16* __restrict__ yscr,
    const int* __restrict__ sel, const int2* __restrict__ slots,
    const float* __restrict__ s_e)
{
    const int t = blockIdx.x;
    const int d = threadIdx.x * 8;
    const int2 sl = slots[t];
    const float se0 = s_e[sel[2 * t]];
    const float se1 = s_e[sel[2 * t + 1]];
    bfrag y0 = *(const bfrag*)&yscr[(size_t)sl.x * DIM + d];
    bfrag y1 = *(const bfrag*)&yscr[(size_t)sl.y * DIM + d];
    float4* o = (float4*)(out + (size_t)t * DIM + d);
    float4 o0 = o[0], o1 = o[1];
    o0.x += se0 * bf2f(y0[0]) + se1 * bf2f(y1[0]);
    o0.y += se0 * bf2f(y0[1]) + se1 * bf2f(y1[1]);
    o0.z += se0 * bf2f(y0[2]) + se1 * bf2f(y1[2]);
    o0.w += se0 * bf2f(y0[3]) + se1 * bf2f(y1[3]);
    o1.x += se0 * bf2f(y0[4]) + se1 * bf2f(y1[4]);
    o1.y += se0 * bf2f(y0[5]) + se1 * bf2f(y1[5]);
    o1.z += se0 * bf2f(y0[6]) + se1 * bf2f(y1[6]);
    o1.w += se0 * bf2f(y0[7]) + se1 * bf2f(y1[7]);
    o[0] = o0; o[1] = o1;
}

extern "C" void kernel_launch(void* const* d_in, const int* in_sizes, int n_in,
                              void* d_out, int out_size, void* d_ws, size_t ws_size,
                              hipStream_t stream) {
    const float* x   = (const float*)d_in[0];
    const float* gw  = (const float*)d_in[1];
    const float* w1  = (const float*)d_in[2];
    const float* w3  = (const float*)d_in[3];
    const float* w2  = (const float*)d_in[4];
    const float* sw1 = (const float*)d_in[5];
    const float* sw3 = (const float*)d_in[6];
    const float* sw2 = (const float*)d_in[7];
    float* out = (float*)d_out;

    const size_t SZ_X    = (size_t)T_TOK * DIM * 2;           // 33.6 MB
    const size_t SZ_W    = (size_t)NEXP * HDIM * DIM * 2;     // 46.1 MB each
    const size_t SZ_SW   = (size_t)SHDIM * DIM * 2;           // 11.5 MB each
    const size_t SZ_ACTS = (size_t)T_TOK * SHDIM * 2;         // 46.1 MB
    const size_t SZ_ACTE = (size_t)2 * T_TOK * HDIM * 2;      // 46.1 MB
    const size_t SZ_INTS = (size_t)6 * T_TOK * sizeof(int) + 512;
    const size_t need_base   = SZ_X + 3 * SZ_W + 3 * SZ_SW + SZ_ACTS + SZ_INTS;
    const size_t need_merged = need_base + SZ_ACTE;           // ~299 MB (fit confirmed R10)

    char* p = (char*)d_ws;
    __hip_bfloat16* xbf   = (__hip_bfloat16*)p; p += SZ_X;
    __hip_bfloat16* w1bf  = (__hip_bfloat16*)p; p += SZ_W;
    __hip_bfloat16* w3bf  = (__hip_bfloat16*)p; p += SZ_W;
    __hip_bfloat16* w2bf  = (__hip_bfloat16*)p; p += SZ_W;
    __hip_bfloat16* sw1bf = (__hip_bfloat16*)p; p += SZ_SW;
    __hip_bfloat16* sw3bf = (__hip_bfloat16*)p; p += SZ_SW;
    __hip_bfloat16* sw2bf = (__hip_bfloat16*)p; p += SZ_SW;
    __hip_bfloat16* act_sh = (__hip_bfloat16*)p; p += SZ_ACTS;
    const bool merged = (need_merged <= ws_size);
    __hip_bfloat16* act_ex = merged ? (__hip_bfloat16*)p : act_sh;  // fallback aliases
    if (merged) p += SZ_ACTE;
    int*  list  = (int*)p;  p += (size_t)2 * T_TOK * sizeof(int);
    int*  sel   = (int*)p;  p += (size_t)2 * T_TOK * sizeof(int);
    int2* slots = (int2*)p; p += (size_t)2 * T_TOK * sizeof(int);
    int*  meta  = (int*)p;
    float* s_e  = (float*)(meta + 32);
    // yscr (64 MB) aliases xbf+w1bf (dead once the expert-up work finishes)
    __hip_bfloat16* yscr = (__hip_bfloat16*)d_ws;
    if (need_base > ws_size) return;

    hipMemsetAsync(meta, 0, 256, stream);
    gate_kernel<<<T_TOK / 32, 256, 0, stream>>>(x, gw, xbf, sel, meta, s_e);
    scan_kernel<<<1, 64, 0, stream>>>(meta);
    fill_kernel<<<T_TOK / 256, 256, 0, stream>>>(sel, meta, list, slots);
    cvt6_kernel<<<2048, 256, 0, stream>>>(w1, w3, w2, sw1, sw3, sw2,
                                          w1bf, w3bf, w2bf, sw1bf, sw3bf, sw2bf);

    if (merged) {
        up_k<SHDIM, false><<<dim3(SHDIM / 128, T_TOK / 256, 1), 512, 0, stream>>>(
            xbf, sw1bf, sw3bf, act_sh, nullptr, meta);
        mid_merged<<<256 + 2816, 512, 0, stream>>>(
            act_sh, sw2bf, out, xbf, w1bf, w3bf, act_ex, list, meta);
        down_k<HDIM, true><<<dim3(DIM / 256, T_TOK / 256, NEXP), 512, 0, stream>>>(
            act_ex, w2bf, out, yscr, meta);
    } else {
        // sequential fallback (R7 ordering, act buffers aliased)
        up_k<SHDIM, false><<<dim3(SHDIM / 128, T_TOK / 256, 1), 512, 0, stream>>>(
            xbf, sw1bf, sw3bf, act_sh, nullptr, meta);
        down_k<SHDIM, false><<<dim3(DIM / 256, T_TOK / 256, 1), 512, 0, stream>>>(
            act_sh, sw2bf, out, nullptr, meta);
        up_k<HDIM, true><<<dim3(HDIM / 128, T_TOK / 256, NEXP), 512, 0, stream>>>(
            xbf, w1bf, w3bf, act_ex, list, meta);
        down_k<HDIM, true><<<dim3(DIM / 256, T_TOK / 256, NEXP), 512, 0, stream>>>(
            act_ex, w2bf, out, yscr, meta);
    }
    combine_kernel<<<T_TOK, 256, 0, stream>>>(out, yscr, sel, slots, s_e);
}

// Round 13
// 987.768 us; speedup vs baseline: 2.7367x; 1.0128x over previous
//
#include <hip/hip_runtime.h>
#include <hip/hip_bf16.h>
#include <stdint.h>

#define T_TOK 8192
#define DIM   2048
#define NEXP  8
#define HDIM  1408
#define SHDIM 2816

typedef __attribute__((ext_vector_type(8))) short bfrag;   // 8 x bf16 (4 VGPR)
typedef __attribute__((ext_vector_type(4))) float f32x4;
typedef __attribute__((ext_vector_type(4))) short s16x4;

__device__ __forceinline__ short f2bf(float f) {
    union { float f; uint32_t u; } v; v.f = f;
    return (short)((v.u + 0x8000u) >> 16);   // round-half-up bf16
}
__device__ __forceinline__ float bf2f(short s) {
    union { uint32_t u; float f; } v; v.u = ((uint32_t)(uint16_t)s) << 16;
    return v.f;
}

__device__ __forceinline__ bfrag cvt8(float4 a, float4 b) {
    bfrag r;
    r[0] = f2bf(a.x); r[1] = f2bf(a.y); r[2] = f2bf(a.z); r[3] = f2bf(a.w);
    r[4] = f2bf(b.x); r[5] = f2bf(b.y); r[6] = f2bf(b.z); r[7] = f2bf(b.w);
    return r;
}

__device__ __forceinline__ void gload16(const void* g, void* l) {
    __builtin_amdgcn_global_load_lds(
        (__attribute__((address_space(1))) void*)(g),
        (__attribute__((address_space(3))) void*)(l), 16, 0, 0);
}

#define MFMA16(a, b, c) __builtin_amdgcn_mfma_f32_16x16x32_bf16((a), (b), (c), 0, 0, 0)

// meta: ints [0..7] counts, [8..15] cursor, [16..24] offsets; floats at +32: s_e[8]

// ---- dispatch 1: gate (256 blocks) + sw1/sw3 cvt workers (256 blocks) ----
__global__ __launch_bounds__(256) void gate_cvt_kernel(
    const float* __restrict__ x, const float* __restrict__ gw,
    __hip_bfloat16* __restrict__ xbf,
    int* __restrict__ sel, int* __restrict__ meta, float* __restrict__ s_e,
    const float* __restrict__ sw1f, const float* __restrict__ sw3f,
    __hip_bfloat16* __restrict__ sw1bf, __hip_bfloat16* __restrict__ sw3bf)
{
    const int bid = blockIdx.x;
    if (bid >= T_TOK / 32) {
        // cvt worker: sw1+sw3, 2048 elems/chunk (256 thr x 8)
        constexpr size_t E_SW = (size_t)SHDIM * DIM;   // 5,767,168
        constexpr int NCH = (int)(2 * E_SW / 2048);    // 5632
        const int w = bid - T_TOK / 32;
        for (int c = w; c < NCH; c += 256) {
            size_t elem = (size_t)c * 2048 + threadIdx.x * 8;
            const float* s; __hip_bfloat16* d;
            if (elem < E_SW) { s = sw1f + elem; d = sw1bf + elem; }
            else             { s = sw3f + (elem - E_SW); d = sw3bf + (elem - E_SW); }
            float4 a = ((const float4*)s)[0], b = ((const float4*)s)[1];
            *(bfrag*)d = cvt8(a, b);
        }
        return;
    }
    __shared__ float g[NEXP * DIM];            // 64 KB
    for (int i = threadIdx.x; i < NEXP * DIM; i += 256) g[i] = gw[i];
    __syncthreads();
    const int wid = threadIdx.x >> 6, lane = threadIdx.x & 63;
    for (int it = 0; it < 8; ++it) {
        const int t = bid * 32 + wid * 8 + it;
        float acc[NEXP];
#pragma unroll
        for (int e = 0; e < NEXP; ++e) acc[e] = 0.f;
        const float4* xr = (const float4*)(x + (size_t)t * DIM);
        for (int j = 0; j < DIM / 4; j += 64) {
            float4 xv = xr[j + lane];
            s16x4 xv16 = { f2bf(xv.x), f2bf(xv.y), f2bf(xv.z), f2bf(xv.w) };
            *(s16x4*)&xbf[(size_t)t * DIM + (j + lane) * 4] = xv16;
#pragma unroll
            for (int e = 0; e < NEXP; ++e) {
                float4 gv = *(const float4*)&g[e * DIM + (j + lane) * 4];
                acc[e] += xv.x * gv.x + xv.y * gv.y + xv.z * gv.z + xv.w * gv.w;
            }
        }
#pragma unroll
        for (int e = 0; e < NEXP; ++e)
            for (int o = 32; o; o >>= 1) acc[e] += __shfl_xor(acc[e], o);
        if (lane == 0) {
            int e0 = 0; float v0 = acc[0];
#pragma unroll
            for (int e = 1; e < NEXP; ++e) if (acc[e] > v0) { v0 = acc[e]; e0 = e; }
            int e1 = -1; float v1 = -3.4e38f;
#pragma unroll
            for (int e = 0; e < NEXP; ++e) if (e != e0 && acc[e] > v1) { v1 = acc[e]; e1 = e; }
            float p0 = 1.f / (1.f + __expf(v1 - v0));
            float p1 = 1.f - p0;
            sel[2 * t] = e0; sel[2 * t + 1] = e1;
            atomicAdd(&s_e[e0], p0); atomicAdd(&s_e[e1], p1);
            atomicAdd(&meta[e0], 1); atomicAdd(&meta[e1], 1);
        }
    }
}

__global__ void scan_kernel(int* meta) {
    if (threadIdx.x == 0) {
        int acc = 0;
        for (int e = 0; e < NEXP; ++e) {
            meta[16 + e] = acc;
            meta[8 + e]  = acc;
            acc += meta[e];
        }
        meta[24] = acc;
    }
}

__global__ __launch_bounds__(256) void fill_kernel(
    const int* __restrict__ sel, int* __restrict__ meta,
    int* __restrict__ list, int2* __restrict__ slots)
{
    const int t = blockIdx.x * 256 + threadIdx.x;
    int e0 = sel[2 * t], e1 = sel[2 * t + 1];
    int p0 = atomicAdd(&meta[8 + e0], 1); list[p0] = t;
    int p1 = atomicAdd(&meta[8 + e1], 1); list[p1] = t;
    slots[t] = make_int2(p0, p1);
}

// ============ GEMM cores: R3-dbuf 2-barrier loop (best measured) ============
// 8 waves (2x4), 512 threads, 128 KB LDS (passed in). 0-conflict swizzle:
// row r, slot g: byte = r*128 + ((g^(r&7))<<4); linear gload dest +
// inverse-swizzled global source (rule 21).

template<int N, bool GATHER>
__device__ __forceinline__ void up_core(
    const __hip_bfloat16* __restrict__ X,
    const __hip_bfloat16* __restrict__ B1p,
    const __hip_bfloat16* __restrict__ B3p,
    __hip_bfloat16* __restrict__ actp,
    const int* __restrict__ list,
    int base, int count, int m0, int n0, short* lds)
{
    constexpr int K = DIM;
    constexpr int NT = K / 64;
    short (*As)[256 * 64]  = (short (*)[256 * 64])lds;            // 64 KB
    short (*B1s)[128 * 64] = (short (*)[128 * 64])(lds + 32768);  // 32 KB
    short (*B3s)[128 * 64] = (short (*)[128 * 64])(lds + 49152);  // 32 KB

    const int tid = threadIdx.x, wid = tid >> 6, lane = tid & 63;
    const int rlo = lane >> 3;
    const int swslot = (lane & 7) ^ rlo;

    const __hip_bfloat16* pA[4];
#pragma unroll
    for (int q = 0; q < 4; ++q) {
        int row = (q * 8 + wid) * 8 + rlo;   // 0..255
        int r = m0 + row; if (r > count - 1) r = count - 1;
        int ga = GATHER ? list[base + r] : r;
        pA[q] = X + (size_t)ga * K + swslot * 8;
    }
    const __hip_bfloat16* pB1[2];
    const __hip_bfloat16* pB3[2];
#pragma unroll
    for (int q = 0; q < 2; ++q) {
        int row = (q * 8 + wid) * 8 + rlo;   // 0..127
        pB1[q] = B1p + (size_t)(n0 + row) * K + swslot * 8;
        pB3[q] = B3p + (size_t)(n0 + row) * K + swslot * 8;
    }

#define STAGE_UP(T, BUF) do { const int k0_ = (T) * 64;                         \
    _Pragma("unroll") for (int q = 0; q < 4; ++q)                               \
        gload16(pA[q] + k0_, &As[BUF][(q * 8 + wid) * 512]);                    \
    _Pragma("unroll") for (int q = 0; q < 2; ++q) {                             \
        gload16(pB1[q] + k0_, &B1s[BUF][(q * 8 + wid) * 512]);                  \
        gload16(pB3[q] + k0_, &B3s[BUF][(q * 8 + wid) * 512]); } } while (0)

    const int wm = wid >> 2, wn = wid & 3;
    const int l15 = lane & 15, lhi = lane >> 4;

    f32x4 accg[8][2], accu[8][2];
#pragma unroll
    for (int i = 0; i < 8; ++i)
#pragma unroll
        for (int j = 0; j < 2; ++j) { accg[i][j] = 0.f; accu[i][j] = 0.f; }

    STAGE_UP(0, 0);
    __syncthreads();
    int cur = 0;
#pragma unroll 1
    for (int t = 0; t < NT; ++t) {
        if (t + 1 < NT) STAGE_UP(t + 1, cur ^ 1);
        __builtin_amdgcn_sched_barrier(0);
        bfrag b1f[2][2], b3f[2][2];
#pragma unroll
        for (int j = 0; j < 2; ++j)
#pragma unroll
            for (int kk = 0; kk < 2; ++kk) {
                int rb = wn * 32 + j * 16 + l15;
                int c = kk * 4 + lhi;
                int off = rb * 128 + ((c ^ (rb & 7)) << 4);
                b1f[j][kk] = *(const bfrag*)((const char*)B1s[cur] + off);
                b3f[j][kk] = *(const bfrag*)((const char*)B3s[cur] + off);
            }
        __builtin_amdgcn_s_setprio(1);
#pragma unroll
        for (int i = 0; i < 8; ++i) {
            int ra = wm * 128 + i * 16 + l15;
            const char* abase = (const char*)As[cur] + ra * 128;
            bfrag a0 = *(const bfrag*)(abase + ((lhi       ^ (ra & 7)) << 4));
            bfrag a1 = *(const bfrag*)(abase + (((4 + lhi) ^ (ra & 7)) << 4));
#pragma unroll
            for (int j = 0; j < 2; ++j) {
                accg[i][j] = MFMA16(a0, b1f[j][0], accg[i][j]);
                accu[i][j] = MFMA16(a0, b3f[j][0], accu[i][j]);
                accg[i][j] = MFMA16(a1, b1f[j][1], accg[i][j]);
                accu[i][j] = MFMA16(a1, b3f[j][1], accu[i][j]);
            }
        }
        __builtin_amdgcn_s_setprio(0);
        __syncthreads();
        cur ^= 1;
    }
#undef STAGE_UP

#pragma unroll
    for (int i = 0; i < 8; ++i)
#pragma unroll
        for (int r = 0; r < 4; ++r) {
            int m = wm * 128 + i * 16 + lhi * 4 + r;
            if (m0 + m < count) {
#pragma unroll
                for (int j = 0; j < 2; ++j) {
                    float gg = accg[i][j][r];
                    float uu = accu[i][j][r];
                    float a = gg / (1.f + __expf(-gg)) * uu;   // silu(g)*u
                    int n = n0 + wn * 32 + j * 16 + l15;
                    actp[(size_t)(base + m0 + m) * N + n] = __float2bfloat16(a);
                }
            }
        }
}

template<int KD, bool TO_BF16>
__device__ __forceinline__ void down_core(
    const __hip_bfloat16* __restrict__ Ap,
    const __hip_bfloat16* __restrict__ Bp,
    float* __restrict__ out, __hip_bfloat16* __restrict__ yscr,
    int base, int count, int m0, int n0, short* lds)
{
    constexpr int NT = KD / 64;
    short (*As)[256 * 64] = (short (*)[256 * 64])lds;             // 64 KB
    short (*Bs)[256 * 64] = (short (*)[256 * 64])(lds + 32768);   // 64 KB

    const int tid = threadIdx.x, wid = tid >> 6, lane = tid & 63;
    const int rlo = lane >> 3;
    const int swslot = (lane & 7) ^ rlo;

    const __hip_bfloat16* pA[4];
    const __hip_bfloat16* pB[4];
#pragma unroll
    for (int q = 0; q < 4; ++q) {
        int row = (q * 8 + wid) * 8 + rlo;   // 0..255
        int r = m0 + row; if (r > count - 1) r = count - 1;
        pA[q] = Ap + (size_t)(base + r) * KD + swslot * 8;
        pB[q] = Bp + (size_t)(n0 + row) * KD + swslot * 8;
    }

#define STAGE_DN(T, BUF) do { const int k0_ = (T) * 64;                         \
    _Pragma("unroll") for (int q = 0; q < 4; ++q) {                             \
        gload16(pA[q] + k0_, &As[BUF][(q * 8 + wid) * 512]);                    \
        gload16(pB[q] + k0_, &Bs[BUF][(q * 8 + wid) * 512]); } } while (0)

    const int wm = wid >> 2, wn = wid & 3;
    const int l15 = lane & 15, lhi = lane >> 4;

    f32x4 acc[8][4];
#pragma unroll
    for (int i = 0; i < 8; ++i)
#pragma unroll
        for (int j = 0; j < 4; ++j) acc[i][j] = 0.f;

    STAGE_DN(0, 0);
    __syncthreads();
    int cur = 0;
#pragma unroll 1
    for (int t = 0; t < NT; ++t) {
        if (t + 1 < NT) STAGE_DN(t + 1, cur ^ 1);
        __builtin_amdgcn_sched_barrier(0);
        bfrag bf[4][2];
#pragma unroll
        for (int j = 0; j < 4; ++j)
#pragma unroll
            for (int kk = 0; kk < 2; ++kk) {
                int rb = wn * 64 + j * 16 + l15;
                int c = kk * 4 + lhi;
                bf[j][kk] = *(const bfrag*)((const char*)Bs[cur] + rb * 128 + ((c ^ (rb & 7)) << 4));
            }
        __builtin_amdgcn_s_setprio(1);
#pragma unroll
        for (int i = 0; i < 8; ++i) {
            int ra = wm * 128 + i * 16 + l15;
            const char* abase = (const char*)As[cur] + ra * 128;
            bfrag a0 = *(const bfrag*)(abase + ((lhi       ^ (ra & 7)) << 4));
            bfrag a1 = *(const bfrag*)(abase + (((4 + lhi) ^ (ra & 7)) << 4));
#pragma unroll
            for (int j = 0; j < 4; ++j) {
                acc[i][j] = MFMA16(a0, bf[j][0], acc[i][j]);
                acc[i][j] = MFMA16(a1, bf[j][1], acc[i][j]);
            }
        }
        __builtin_amdgcn_s_setprio(0);
        __syncthreads();
        cur ^= 1;
    }
#undef STAGE_DN

#pragma unroll
    for (int i = 0; i < 8; ++i)
#pragma unroll
        for (int r = 0; r < 4; ++r) {
            int m = wm * 128 + i * 16 + lhi * 4 + r;
            if (m0 + m < count) {
#pragma unroll
                for (int j = 0; j < 4; ++j) {
                    int n = n0 + wn * 64 + j * 16 + l15;
                    if (TO_BF16)
                        yscr[(size_t)(base + m0 + m) * DIM + n] = __float2bfloat16(acc[i][j][r]);
                    else
                        out[(size_t)(m0 + m) * DIM + n] = acc[i][j][r];
                }
            }
        }
}

// ---- dispatch 2: up_shared (704 blocks) + w1/w3/w2/sw2 cvt workers (512) ----
#define UPSH_NG 704
#define UPSH_NCVT 512
__global__ __launch_bounds__(512, 2) void upsh_cvt_k(
    const __hip_bfloat16* __restrict__ X,
    const __hip_bfloat16* __restrict__ SW1, const __hip_bfloat16* __restrict__ SW3,
    __hip_bfloat16* __restrict__ act_sh,
    const float* __restrict__ w1f, const float* __restrict__ w3f,
    const float* __restrict__ w2f, const float* __restrict__ sw2f,
    __hip_bfloat16* __restrict__ w1bf, __hip_bfloat16* __restrict__ w3bf,
    __hip_bfloat16* __restrict__ w2bf, __hip_bfloat16* __restrict__ sw2bf)
{
    const int bid = blockIdx.x;
    if (bid >= UPSH_NG) {
        // cvt worker: 4096 elems/chunk (512 thr x 8)
        constexpr size_t E_W  = (size_t)NEXP * HDIM * DIM;  // 23,068,672
        constexpr size_t E_SW = (size_t)SHDIM * DIM;        //  5,767,168
        constexpr int NCH = (int)((3 * E_W + E_SW) / 4096); // 18,304
        const int w = bid - UPSH_NG;
        for (int c = w; c < NCH; c += UPSH_NCVT) {
            size_t elem = (size_t)c * 4096 + threadIdx.x * 8;
            const float* s; __hip_bfloat16* d;
            if      (elem < E_W)          { s = w1f + elem;               d = w1bf + elem; }
            else if (elem < 2 * E_W)      { s = w3f + (elem - E_W);       d = w3bf + (elem - E_W); }
            else if (elem < 3 * E_W)      { s = w2f + (elem - 2 * E_W);   d = w2bf + (elem - 2 * E_W); }
            else                          { s = sw2f + (elem - 3 * E_W);  d = sw2bf + (elem - 3 * E_W); }
            float4 a = ((const float4*)s)[0], b = ((const float4*)s)[1];
            *(bfrag*)d = cvt8(a, b);
        }
        return;
    }
    constexpr int nx = SHDIM / 128, cpx = UPSH_NG / 8;   // 22, 88
    const int virt = (bid & 7) * cpx + (bid >> 3);
    const int xi = virt % nx, yi = virt / nx;
    __shared__ alignas(16) short lds[65536];   // 128 KB
    up_core<SHDIM, false>(X, SW1, SW3, act_sh, nullptr, 0, T_TOK, yi * 256, xi * 128, lds);
}

template<int KD, bool TO_BF16>
__global__ __launch_bounds__(512, 2) void down_k(
    const __hip_bfloat16* __restrict__ A, const __hip_bfloat16* __restrict__ W2,
    float* __restrict__ out, __hip_bfloat16* __restrict__ yscr,
    const int* __restrict__ meta)
{
    constexpr int nx = DIM / 256, ny = T_TOK / 256, nz = TO_BF16 ? NEXP : 1;
    constexpr int nwg = nx * ny * nz, cpx = nwg / 8;
    const int bid = (int)blockIdx.x + nx * ((int)blockIdx.y + ny * (int)blockIdx.z);
    const int virt = (bid & 7) * cpx + (bid >> 3);
    const int xi = virt % nx, rest = virt / nx, yi = rest % ny, e = rest / ny;
    int count, base;
    if (TO_BF16) { count = meta[e]; base = meta[16 + e]; if (yi * 256 >= count) return; }
    else { count = T_TOK; base = 0; }
    __shared__ alignas(16) short lds[65536];
    down_core<KD, TO_BF16>(A, W2 + (size_t)e * DIM * KD, out, yscr,
                           base, count, yi * 256, xi * 256, lds);
}

template<int N, bool GATHER>
__global__ __launch_bounds__(512, 2) void up_k(
    const __hip_bfloat16* __restrict__ X,
    const __hip_bfloat16* __restrict__ W1, const __hip_bfloat16* __restrict__ W3,
    __hip_bfloat16* __restrict__ act,
    const int* __restrict__ list, const int* __restrict__ meta)
{
    constexpr int nx = N / 128, ny = T_TOK / 256, nz = GATHER ? NEXP : 1;
    constexpr int nwg = nx * ny * nz, cpx = nwg / 8;
    const int bid = (int)blockIdx.x + nx * ((int)blockIdx.y + ny * (int)blockIdx.z);
    const int virt = (bid & 7) * cpx + (bid >> 3);
    const int xi = virt % nx, rest = virt / nx, yi = rest % ny, e = rest / ny;
    int count, base;
    if (GATHER) { count = meta[e]; base = meta[16 + e]; if (yi * 256 >= count) return; }
    else { count = T_TOK; base = 0; }
    __shared__ alignas(16) short lds[65536];
    up_core<N, GATHER>(X, W1 + (size_t)e * N * DIM, W3 + (size_t)e * N * DIM,
                       act, list, base, count, yi * 256, xi * 128, lds);
}

// merged middle dispatch: down-shared (256 blocks) + up-expert (2816 blocks).
__global__ __launch_bounds__(512, 2) void mid_merged(
    const __hip_bfloat16* __restrict__ act_sh, const __hip_bfloat16* __restrict__ sw2bf,
    float* __restrict__ out,
    const __hip_bfloat16* __restrict__ xbf,
    const __hip_bfloat16* __restrict__ w1bf, const __hip_bfloat16* __restrict__ w3bf,
    __hip_bfloat16* __restrict__ act_ex,
    const int* __restrict__ list, const int* __restrict__ meta)
{
    __shared__ alignas(16) short lds[65536];
    const int bid = (int)blockIdx.x;
    if (bid < 256) {
        constexpr int cpx = 256 / 8;
        const int virt = (bid & 7) * cpx + (bid >> 3);
        const int n0 = (virt & 7) * 256, m0 = (virt >> 3) * 256;
        down_core<SHDIM, false>(act_sh, sw2bf, out, nullptr, 0, T_TOK, m0, n0, lds);
    } else {
        const int b = bid - 256;                 // 256 % 8 == 0: b%8 still = XCD
        constexpr int cpx = 2816 / 8;
        const int virt = (b & 7) * cpx + (b >> 3);
        const int e = virt / 352, r = virt % 352;
        const int n0 = (r % 11) * 128, m0 = (r / 11) * 256;
        const int count = meta[e], base = meta[16 + e];
        if (m0 >= count) return;
        up_core<HDIM, true>(xbf, w1bf + (size_t)e * HDIM * DIM, w3bf + (size_t)e * HDIM * DIM,
                            act_ex, list, base, count, m0, n0, lds);
    }
}

// out[t] += s_e[e0]*y[slot0] + s_e[e1]*y[slot1]
__global__ __launch_bounds__(256) void combine_kernel(
    float* __restrict__ out, const __hip_bfloat16* __restrict__ yscr,
    const int* __restrict__ sel, const int2* __restrict__ slots,
    const float* __restrict__ s_e)
{
    const int t = blockIdx.x;
    const int d = threadIdx.x * 8;
    const int2 sl = slots[t];
    const float se0 = s_e[sel[2 * t]];
    const float se1 = s_e[sel[2 * t + 1]];
    bfrag y0 = *(const bfrag*)&yscr[(size_t)sl.x * DIM + d];
    bfrag y1 = *(const bfrag*)&yscr[(size_t)sl.y * DIM + d];
    float4* o = (float4*)(out + (size_t)t * DIM + d);
    float4 o0 = o[0], o1 = o[1];
    o0.x += se0 * bf2f(y0[0]) + se1 * bf2f(y1[0]);
    o0.y += se0 * bf2f(y0[1]) + se1 * bf2f(y1[1]);
    o0.z += se0 * bf2f(y0[2]) + se1 * bf2f(y1[2]);
    o0.w += se0 * bf2f(y0[3]) + se1 * bf2f(y1[3]);
    o1.x += se0 * bf2f(y0[4]) + se1 * bf2f(y1[4]);
    o1.y += se0 * bf2f(y0[5]) + se1 * bf2f(y1[5]);
    o1.z += se0 * bf2f(y0[6]) + se1 * bf2f(y1[6]);
    o1.w += se0 * bf2f(y0[7]) + se1 * bf2f(y1[7]);
    o[0] = o0; o[1] = o1;
}

extern "C" void kernel_launch(void* const* d_in, const int* in_sizes, int n_in,
                              void* d_out, int out_size, void* d_ws, size_t ws_size,
                              hipStream_t stream) {
    const float* x   = (const float*)d_in[0];
    const float* gw  = (const float*)d_in[1];
    const float* w1  = (const float*)d_in[2];
    const float* w3  = (const float*)d_in[3];
    const float* w2  = (const float*)d_in[4];
    const float* sw1 = (const float*)d_in[5];
    const float* sw3 = (const float*)d_in[6];
    const float* sw2 = (const float*)d_in[7];
    float* out = (float*)d_out;

    const size_t SZ_X    = (size_t)T_TOK * DIM * 2;           // 33.6 MB
    const size_t SZ_W    = (size_t)NEXP * HDIM * DIM * 2;     // 46.1 MB each
    const size_t SZ_SW   = (size_t)SHDIM * DIM * 2;           // 11.5 MB each
    const size_t SZ_ACTS = (size_t)T_TOK * SHDIM * 2;         // 46.1 MB
    const size_t SZ_ACTE = (size_t)2 * T_TOK * HDIM * 2;      // 46.1 MB
    const size_t SZ_INTS = (size_t)6 * T_TOK * sizeof(int) + 512;
    const size_t need_base   = SZ_X + 3 * SZ_W + 3 * SZ_SW + SZ_ACTS + SZ_INTS;
    const size_t need_merged = need_base + SZ_ACTE;           // ~299 MB (fit confirmed R10)

    char* p = (char*)d_ws;
    __hip_bfloat16* xbf   = (__hip_bfloat16*)p; p += SZ_X;
    __hip_bfloat16* w1bf  = (__hip_bfloat16*)p; p += SZ_W;
    __hip_bfloat16* w3bf  = (__hip_bfloat16*)p; p += SZ_W;
    __hip_bfloat16* w2bf  = (__hip_bfloat16*)p; p += SZ_W;
    __hip_bfloat16* sw1bf = (__hip_bfloat16*)p; p += SZ_SW;
    __hip_bfloat16* sw3bf = (__hip_bfloat16*)p; p += SZ_SW;
    __hip_bfloat16* sw2bf = (__hip_bfloat16*)p; p += SZ_SW;
    __hip_bfloat16* act_sh = (__hip_bfloat16*)p; p += SZ_ACTS;
    const bool merged = (need_merged <= ws_size);
    __hip_bfloat16* act_ex = merged ? (__hip_bfloat16*)p : act_sh;  // fallback aliases
    if (merged) p += SZ_ACTE;
    int*  list  = (int*)p;  p += (size_t)2 * T_TOK * sizeof(int);
    int*  sel   = (int*)p;  p += (size_t)2 * T_TOK * sizeof(int);
    int2* slots = (int2*)p; p += (size_t)2 * T_TOK * sizeof(int);
    int*  meta  = (int*)p;
    float* s_e  = (float*)(meta + 32);
    // yscr (64 MB) aliases xbf+w1bf (dead once the expert-up work finishes)
    __hip_bfloat16* yscr = (__hip_bfloat16*)d_ws;
    if (need_base > ws_size) return;

    hipMemsetAsync(meta, 0, 256, stream);
    gate_cvt_kernel<<<T_TOK / 32 + 256, 256, 0, stream>>>(
        x, gw, xbf, sel, meta, s_e, sw1, sw3, sw1bf, sw3bf);
    scan_kernel<<<1, 64, 0, stream>>>(meta);
    fill_kernel<<<T_TOK / 256, 256, 0, stream>>>(sel, meta, list, slots);

    upsh_cvt_k<<<UPSH_NG + UPSH_NCVT, 512, 0, stream>>>(
        xbf, sw1bf, sw3bf, act_sh, w1, w3, w2, sw2, w1bf, w3bf, w2bf, sw2bf);

    if (merged) {
        mid_merged<<<256 + 2816, 512, 0, stream>>>(
            act_sh, sw2bf, out, xbf, w1bf, w3bf, act_ex, list, meta);
        down_k<HDIM, true><<<dim3(DIM / 256, T_TOK / 256, NEXP), 512, 0, stream>>>(
            act_ex, w2bf, out, yscr, meta);
    } else {
        down_k<SHDIM, false><<<dim3(DIM / 256, T_TOK / 256, 1), 512, 0, stream>>>(
            act_sh, sw2bf, out, nullptr, meta);
        up_k<HDIM, true><<<dim3(HDIM / 128, T_TOK / 256, NEXP), 512, 0, stream>>>(
            xbf, w1bf, w3bf, act_ex, list, meta);
        down_k<HDIM, true><<<dim3(DIM / 256, T_TOK / 256, NEXP), 512, 0, stream>>>(
            act_ex, w2bf, out, yscr, meta);
    }
    combine_kernel<<<T_TOK, 256, 0, stream>>>(out, yscr, sel, slots, s_e);
}

// Round 14
// 963.875 us; speedup vs baseline: 2.8046x; 1.0248x over previous
//
#include <hip/hip_runtime.h>
#include <hip/hip_bf16.h>
#include <stdint.h>

#define T_TOK 8192
#define DIM   2048
#define NEXP  8
#define HDIM  1408
#define SHDIM 2816

typedef __attribute__((ext_vector_type(8))) short bfrag;   // 8 x bf16 (4 VGPR)
typedef __attribute__((ext_vector_type(4))) float f32x4;
typedef __attribute__((ext_vector_type(4))) short s16x4;

__device__ __forceinline__ short f2bf(float f) {
    union { float f; uint32_t u; } v; v.f = f;
    return (short)((v.u + 0x8000u) >> 16);   // round-half-up bf16
}
__device__ __forceinline__ float bf2f(short s) {
    union { uint32_t u; float f; } v; v.u = ((uint32_t)(uint16_t)s) << 16;
    return v.f;
}

__device__ __forceinline__ bfrag cvt8(float4 a, float4 b) {
    bfrag r;
    r[0] = f2bf(a.x); r[1] = f2bf(a.y); r[2] = f2bf(a.z); r[3] = f2bf(a.w);
    r[4] = f2bf(b.x); r[5] = f2bf(b.y); r[6] = f2bf(b.z); r[7] = f2bf(b.w);
    return r;
}

__device__ __forceinline__ void gload16(const void* g, void* l) {
    __builtin_amdgcn_global_load_lds(
        (__attribute__((address_space(1))) void*)(g),
        (__attribute__((address_space(3))) void*)(l), 16, 0, 0);
}

#define MFMA16(a, b, c) __builtin_amdgcn_mfma_f32_16x16x32_bf16((a), (b), (c), 0, 0, 0)

// meta: ints [0..7] counts, [8..15] cursor, [16..24] offsets; floats at +32: s_e[8]

// ---- dispatch 1: gate (256 blocks) + sw1/sw3/sw2 cvt workers (256 blocks) ----
__global__ __launch_bounds__(256) void gate_cvt_kernel(
    const float* __restrict__ x, const float* __restrict__ gw,
    __hip_bfloat16* __restrict__ xbf,
    int* __restrict__ sel, int* __restrict__ meta, float* __restrict__ s_e,
    const float* __restrict__ sw1f, const float* __restrict__ sw3f,
    const float* __restrict__ sw2f,
    __hip_bfloat16* __restrict__ sw1bf, __hip_bfloat16* __restrict__ sw3bf,
    __hip_bfloat16* __restrict__ sw2bf)
{
    const int bid = blockIdx.x;
    if (bid >= T_TOK / 32) {
        // cvt worker: sw1+sw3+sw2, 2048 elems/chunk (256 thr x 8)
        constexpr size_t E_SW = (size_t)SHDIM * DIM;   // 5,767,168
        constexpr int NCH = (int)(3 * E_SW / 2048);    // 8448
        const int w = bid - T_TOK / 32;
        for (int c = w; c < NCH; c += 256) {
            size_t elem = (size_t)c * 2048 + threadIdx.x * 8;
            const float* s; __hip_bfloat16* d;
            if      (elem < E_SW)     { s = sw1f + elem;             d = sw1bf + elem; }
            else if (elem < 2 * E_SW) { s = sw3f + (elem - E_SW);    d = sw3bf + (elem - E_SW); }
            else                      { s = sw2f + (elem - 2 * E_SW); d = sw2bf + (elem - 2 * E_SW); }
            float4 a = ((const float4*)s)[0], b = ((const float4*)s)[1];
            *(bfrag*)d = cvt8(a, b);
        }
        return;
    }
    __shared__ float g[NEXP * DIM];            // 64 KB
    for (int i = threadIdx.x; i < NEXP * DIM; i += 256) g[i] = gw[i];
    __syncthreads();
    const int wid = threadIdx.x >> 6, lane = threadIdx.x & 63;
    for (int it = 0; it < 8; ++it) {
        const int t = bid * 32 + wid * 8 + it;
        float acc[NEXP];
#pragma unroll
        for (int e = 0; e < NEXP; ++e) acc[e] = 0.f;
        const float4* xr = (const float4*)(x + (size_t)t * DIM);
        for (int j = 0; j < DIM / 4; j += 64) {
            float4 xv = xr[j + lane];
            s16x4 xv16 = { f2bf(xv.x), f2bf(xv.y), f2bf(xv.z), f2bf(xv.w) };
            *(s16x4*)&xbf[(size_t)t * DIM + (j + lane) * 4] = xv16;
#pragma unroll
            for (int e = 0; e < NEXP; ++e) {
                float4 gv = *(const float4*)&g[e * DIM + (j + lane) * 4];
                acc[e] += xv.x * gv.x + xv.y * gv.y + xv.z * gv.z + xv.w * gv.w;
            }
        }
#pragma unroll
        for (int e = 0; e < NEXP; ++e)
            for (int o = 32; o; o >>= 1) acc[e] += __shfl_xor(acc[e], o);
        if (lane == 0) {
            int e0 = 0; float v0 = acc[0];
#pragma unroll
            for (int e = 1; e < NEXP; ++e) if (acc[e] > v0) { v0 = acc[e]; e0 = e; }
            int e1 = -1; float v1 = -3.4e38f;
#pragma unroll
            for (int e = 0; e < NEXP; ++e) if (e != e0 && acc[e] > v1) { v1 = acc[e]; e1 = e; }
            float p0 = 1.f / (1.f + __expf(v1 - v0));
            float p1 = 1.f - p0;
            sel[2 * t] = e0; sel[2 * t + 1] = e1;
            atomicAdd(&s_e[e0], p0); atomicAdd(&s_e[e1], p1);
            atomicAdd(&meta[e0], 1); atomicAdd(&meta[e1], 1);
        }
    }
}

__global__ void scan_kernel(int* meta) {
    if (threadIdx.x == 0) {
        int acc = 0;
        for (int e = 0; e < NEXP; ++e) {
            meta[16 + e] = acc;
            meta[8 + e]  = acc;
            acc += meta[e];
        }
        meta[24] = acc;
    }
}

__global__ __launch_bounds__(256) void fill_kernel(
    const int* __restrict__ sel, int* __restrict__ meta,
    int* __restrict__ list, int2* __restrict__ slots)
{
    const int t = blockIdx.x * 256 + threadIdx.x;
    int e0 = sel[2 * t], e1 = sel[2 * t + 1];
    int p0 = atomicAdd(&meta[8 + e0], 1); list[p0] = t;
    int p1 = atomicAdd(&meta[8 + e1], 1); list[p1] = t;
    slots[t] = make_int2(p0, p1);
}

// ============ GEMM cores: R3-dbuf 2-barrier loop (best measured) ============
// 8 waves (2x4), 512 threads, 128 KB LDS (passed in). 0-conflict swizzle:
// row r, slot g: byte = r*128 + ((g^(r&7))<<4); linear gload dest +
// inverse-swizzled global source (rule 21).

template<int N, bool GATHER>
__device__ __forceinline__ void up_core(
    const __hip_bfloat16* __restrict__ X,
    const __hip_bfloat16* __restrict__ B1p,
    const __hip_bfloat16* __restrict__ B3p,
    __hip_bfloat16* __restrict__ actp,
    const int* __restrict__ list,
    int base, int count, int m0, int n0, short* lds)
{
    constexpr int K = DIM;
    constexpr int NT = K / 64;
    short (*As)[256 * 64]  = (short (*)[256 * 64])lds;            // 64 KB
    short (*B1s)[128 * 64] = (short (*)[128 * 64])(lds + 32768);  // 32 KB
    short (*B3s)[128 * 64] = (short (*)[128 * 64])(lds + 49152);  // 32 KB

    const int tid = threadIdx.x, wid = tid >> 6, lane = tid & 63;
    const int rlo = lane >> 3;
    const int swslot = (lane & 7) ^ rlo;

    const __hip_bfloat16* pA[4];
#pragma unroll
    for (int q = 0; q < 4; ++q) {
        int row = (q * 8 + wid) * 8 + rlo;   // 0..255
        int r = m0 + row; if (r > count - 1) r = count - 1;
        int ga = GATHER ? list[base + r] : r;
        pA[q] = X + (size_t)ga * K + swslot * 8;
    }
    const __hip_bfloat16* pB1[2];
    const __hip_bfloat16* pB3[2];
#pragma unroll
    for (int q = 0; q < 2; ++q) {
        int row = (q * 8 + wid) * 8 + rlo;   // 0..127
        pB1[q] = B1p + (size_t)(n0 + row) * K + swslot * 8;
        pB3[q] = B3p + (size_t)(n0 + row) * K + swslot * 8;
    }

#define STAGE_UP(T, BUF) do { const int k0_ = (T) * 64;                         \
    _Pragma("unroll") for (int q = 0; q < 4; ++q)                               \
        gload16(pA[q] + k0_, &As[BUF][(q * 8 + wid) * 512]);                    \
    _Pragma("unroll") for (int q = 0; q < 2; ++q) {                             \
        gload16(pB1[q] + k0_, &B1s[BUF][(q * 8 + wid) * 512]);                  \
        gload16(pB3[q] + k0_, &B3s[BUF][(q * 8 + wid) * 512]); } } while (0)

    const int wm = wid >> 2, wn = wid & 3;
    const int l15 = lane & 15, lhi = lane >> 4;

    f32x4 accg[8][2], accu[8][2];
#pragma unroll
    for (int i = 0; i < 8; ++i)
#pragma unroll
        for (int j = 0; j < 2; ++j) { accg[i][j] = 0.f; accu[i][j] = 0.f; }

    STAGE_UP(0, 0);
    __syncthreads();
    int cur = 0;
#pragma unroll 1
    for (int t = 0; t < NT; ++t) {
        if (t + 1 < NT) STAGE_UP(t + 1, cur ^ 1);
        __builtin_amdgcn_sched_barrier(0);
        bfrag b1f[2][2], b3f[2][2];
#pragma unroll
        for (int j = 0; j < 2; ++j)
#pragma unroll
            for (int kk = 0; kk < 2; ++kk) {
                int rb = wn * 32 + j * 16 + l15;
                int c = kk * 4 + lhi;
                int off = rb * 128 + ((c ^ (rb & 7)) << 4);
                b1f[j][kk] = *(const bfrag*)((const char*)B1s[cur] + off);
                b3f[j][kk] = *(const bfrag*)((const char*)B3s[cur] + off);
            }
        __builtin_amdgcn_s_setprio(1);
#pragma unroll
        for (int i = 0; i < 8; ++i) {
            int ra = wm * 128 + i * 16 + l15;
            const char* abase = (const char*)As[cur] + ra * 128;
            bfrag a0 = *(const bfrag*)(abase + ((lhi       ^ (ra & 7)) << 4));
            bfrag a1 = *(const bfrag*)(abase + (((4 + lhi) ^ (ra & 7)) << 4));
#pragma unroll
            for (int j = 0; j < 2; ++j) {
                accg[i][j] = MFMA16(a0, b1f[j][0], accg[i][j]);
                accu[i][j] = MFMA16(a0, b3f[j][0], accu[i][j]);
                accg[i][j] = MFMA16(a1, b1f[j][1], accg[i][j]);
                accu[i][j] = MFMA16(a1, b3f[j][1], accu[i][j]);
            }
        }
        __builtin_amdgcn_s_setprio(0);
        __syncthreads();
        cur ^= 1;
    }
#undef STAGE_UP

#pragma unroll
    for (int i = 0; i < 8; ++i)
#pragma unroll
        for (int r = 0; r < 4; ++r) {
            int m = wm * 128 + i * 16 + lhi * 4 + r;
            if (m0 + m < count) {
#pragma unroll
                for (int j = 0; j < 2; ++j) {
                    float gg = accg[i][j][r];
                    float uu = accu[i][j][r];
                    float a = gg / (1.f + __expf(-gg)) * uu;   // silu(g)*u
                    int n = n0 + wn * 32 + j * 16 + l15;
                    actp[(size_t)(base + m0 + m) * N + n] = __float2bfloat16(a);
                }
            }
        }
}

template<int KD, bool TO_BF16>
__device__ __forceinline__ void down_core(
    const __hip_bfloat16* __restrict__ Ap,
    const __hip_bfloat16* __restrict__ Bp,
    float* __restrict__ out, __hip_bfloat16* __restrict__ yscr,
    int base, int count, int m0, int n0, short* lds)
{
    constexpr int NT = KD / 64;
    short (*As)[256 * 64] = (short (*)[256 * 64])lds;             // 64 KB
    short (*Bs)[256 * 64] = (short (*)[256 * 64])(lds + 32768);   // 64 KB

    const int tid = threadIdx.x, wid = tid >> 6, lane = tid & 63;
    const int rlo = lane >> 3;
    const int swslot = (lane & 7) ^ rlo;

    const __hip_bfloat16* pA[4];
    const __hip_bfloat16* pB[4];
#pragma unroll
    for (int q = 0; q < 4; ++q) {
        int row = (q * 8 + wid) * 8 + rlo;   // 0..255
        int r = m0 + row; if (r > count - 1) r = count - 1;
        pA[q] = Ap + (size_t)(base + r) * KD + swslot * 8;
        pB[q] = Bp + (size_t)(n0 + row) * KD + swslot * 8;
    }

#define STAGE_DN(T, BUF) do { const int k0_ = (T) * 64;                         \
    _Pragma("unroll") for (int q = 0; q < 4; ++q) {                             \
        gload16(pA[q] + k0_, &As[BUF][(q * 8 + wid) * 512]);                    \
        gload16(pB[q] + k0_, &Bs[BUF][(q * 8 + wid) * 512]); } } while (0)

    const int wm = wid >> 2, wn = wid & 3;
    const int l15 = lane & 15, lhi = lane >> 4;

    f32x4 acc[8][4];
#pragma unroll
    for (int i = 0; i < 8; ++i)
#pragma unroll
        for (int j = 0; j < 4; ++j) acc[i][j] = 0.f;

    STAGE_DN(0, 0);
    __syncthreads();
    int cur = 0;
#pragma unroll 1
    for (int t = 0; t < NT; ++t) {
        if (t + 1 < NT) STAGE_DN(t + 1, cur ^ 1);
        __builtin_amdgcn_sched_barrier(0);
        bfrag bf[4][2];
#pragma unroll
        for (int j = 0; j < 4; ++j)
#pragma unroll
            for (int kk = 0; kk < 2; ++kk) {
                int rb = wn * 64 + j * 16 + l15;
                int c = kk * 4 + lhi;
                bf[j][kk] = *(const bfrag*)((const char*)Bs[cur] + rb * 128 + ((c ^ (rb & 7)) << 4));
            }
        __builtin_amdgcn_s_setprio(1);
#pragma unroll
        for (int i = 0; i < 8; ++i) {
            int ra = wm * 128 + i * 16 + l15;
            const char* abase = (const char*)As[cur] + ra * 128;
            bfrag a0 = *(const bfrag*)(abase + ((lhi       ^ (ra & 7)) << 4));
            bfrag a1 = *(const bfrag*)(abase + (((4 + lhi) ^ (ra & 7)) << 4));
#pragma unroll
            for (int j = 0; j < 4; ++j) {
                acc[i][j] = MFMA16(a0, bf[j][0], acc[i][j]);
                acc[i][j] = MFMA16(a1, bf[j][1], acc[i][j]);
            }
        }
        __builtin_amdgcn_s_setprio(0);
        __syncthreads();
        cur ^= 1;
    }
#undef STAGE_DN

#pragma unroll
    for (int i = 0; i < 8; ++i)
#pragma unroll
        for (int r = 0; r < 4; ++r) {
            int m = wm * 128 + i * 16 + lhi * 4 + r;
            if (m0 + m < count) {
#pragma unroll
                for (int j = 0; j < 4; ++j) {
                    int n = n0 + wn * 64 + j * 16 + l15;
                    if (TO_BF16)
                        yscr[(size_t)(base + m0 + m) * DIM + n] = __float2bfloat16(acc[i][j][r]);
                    else
                        out[(size_t)(m0 + m) * DIM + n] = acc[i][j][r];
                }
            }
        }
}

// ---- dispatch 2: up_shared (704 blocks) + w1/w3 cvt workers (384) ----
#define UPSH_NG 704
#define UPSH_NCVT 384
__global__ __launch_bounds__(512, 2) void upsh_cvt_k(
    const __hip_bfloat16* __restrict__ X,
    const __hip_bfloat16* __restrict__ SW1, const __hip_bfloat16* __restrict__ SW3,
    __hip_bfloat16* __restrict__ act_sh,
    const float* __restrict__ w1f, const float* __restrict__ w3f,
    __hip_bfloat16* __restrict__ w1bf, __hip_bfloat16* __restrict__ w3bf)
{
    const int bid = blockIdx.x;
    if (bid >= UPSH_NG) {
        // cvt worker: w1+w3, 4096 elems/chunk (512 thr x 8)
        constexpr size_t E_W = (size_t)NEXP * HDIM * DIM;   // 23,068,672
        constexpr int NCH = (int)(2 * E_W / 4096);          // 11,264
        const int w = bid - UPSH_NG;
        for (int c = w; c < NCH; c += UPSH_NCVT) {
            size_t elem = (size_t)c * 4096 + threadIdx.x * 8;
            const float* s; __hip_bfloat16* d;
            if (elem < E_W) { s = w1f + elem;         d = w1bf + elem; }
            else            { s = w3f + (elem - E_W); d = w3bf + (elem - E_W); }
            float4 a = ((const float4*)s)[0], b = ((const float4*)s)[1];
            *(bfrag*)d = cvt8(a, b);
        }
        return;
    }
    constexpr int nx = SHDIM / 128, cpx = UPSH_NG / 8;   // 22, 88
    const int virt = (bid & 7) * cpx + (bid >> 3);
    const int xi = virt % nx, yi = virt / nx;
    __shared__ alignas(16) short lds[65536];   // 128 KB
    up_core<SHDIM, false>(X, SW1, SW3, act_sh, nullptr, 0, T_TOK, yi * 256, xi * 128, lds);
}

template<int KD, bool TO_BF16>
__global__ __launch_bounds__(512, 2) void down_k(
    const __hip_bfloat16* __restrict__ A, const __hip_bfloat16* __restrict__ W2,
    float* __restrict__ out, __hip_bfloat16* __restrict__ yscr,
    const int* __restrict__ meta)
{
    constexpr int nx = DIM / 256, ny = T_TOK / 256, nz = TO_BF16 ? NEXP : 1;
    constexpr int nwg = nx * ny * nz, cpx = nwg / 8;
    const int bid = (int)blockIdx.x + nx * ((int)blockIdx.y + ny * (int)blockIdx.z);
    const int virt = (bid & 7) * cpx + (bid >> 3);
    const int xi = virt % nx, rest = virt / nx, yi = rest % ny, e = rest / ny;
    int count, base;
    if (TO_BF16) { count = meta[e]; base = meta[16 + e]; if (yi * 256 >= count) return; }
    else { count = T_TOK; base = 0; }
    __shared__ alignas(16) short lds[65536];
    down_core<KD, TO_BF16>(A, W2 + (size_t)e * DIM * KD, out, yscr,
                           base, count, yi * 256, xi * 256, lds);
}

template<int N, bool GATHER>
__global__ __launch_bounds__(512, 2) void up_k(
    const __hip_bfloat16* __restrict__ X,
    const __hip_bfloat16* __restrict__ W1, const __hip_bfloat16* __restrict__ W3,
    __hip_bfloat16* __restrict__ act,
    const int* __restrict__ list, const int* __restrict__ meta)
{
    constexpr int nx = N / 128, ny = T_TOK / 256, nz = GATHER ? NEXP : 1;
    constexpr int nwg = nx * ny * nz, cpx = nwg / 8;
    const int bid = (int)blockIdx.x + nx * ((int)blockIdx.y + ny * (int)blockIdx.z);
    const int virt = (bid & 7) * cpx + (bid >> 3);
    const int xi = virt % nx, rest = virt / nx, yi = rest % ny, e = rest / ny;
    int count, base;
    if (GATHER) { count = meta[e]; base = meta[16 + e]; if (yi * 256 >= count) return; }
    else { count = T_TOK; base = 0; }
    __shared__ alignas(16) short lds[65536];
    up_core<N, GATHER>(X, W1 + (size_t)e * N * DIM, W3 + (size_t)e * N * DIM,
                       act, list, base, count, yi * 256, xi * 128, lds);
}

// fallback-only: w2 conversion
__global__ __launch_bounds__(256) void cvt_w2_kernel(
    const float* __restrict__ w2f, __hip_bfloat16* __restrict__ w2bf)
{
    constexpr size_t E_W = (size_t)NEXP * HDIM * DIM;
    const int stride = gridDim.x * 256;
    for (size_t i = blockIdx.x * 256 + threadIdx.x; i < E_W / 8; i += stride) {
        const float4* p = (const float4*)(w2f + i * 8);
        float4 a = p[0], b = p[1];
        *(bfrag*)(w2bf + i * 8) = cvt8(a, b);
    }
}

// middle dispatch: down-shared (256) + up-expert (2816) + w2 cvt workers (256).
// Roles independent; w2bf consumed only by the NEXT dispatch (down_expert).
#define MID_NDS 256
#define MID_NUE 2816
#define MID_NCVT 256
__global__ __launch_bounds__(512, 2) void mid_merged(
    const __hip_bfloat16* __restrict__ act_sh, const __hip_bfloat16* __restrict__ sw2bf,
    float* __restrict__ out,
    const __hip_bfloat16* __restrict__ xbf,
    const __hip_bfloat16* __restrict__ w1bf, const __hip_bfloat16* __restrict__ w3bf,
    __hip_bfloat16* __restrict__ act_ex,
    const int* __restrict__ list, const int* __restrict__ meta,
    const float* __restrict__ w2f, __hip_bfloat16* __restrict__ w2bf)
{
    const int bid = (int)blockIdx.x;
    if (bid >= MID_NDS + MID_NUE) {
        // w2 cvt worker: 4096 elems/chunk (512 thr x 8)
        constexpr size_t E_W = (size_t)NEXP * HDIM * DIM;   // 23,068,672
        constexpr int NCH = (int)(E_W / 4096);              // 5632
        const int w = bid - (MID_NDS + MID_NUE);
        for (int c = w; c < NCH; c += MID_NCVT) {
            size_t elem = (size_t)c * 4096 + threadIdx.x * 8;
            float4 a = ((const float4*)(w2f + elem))[0];
            float4 b = ((const float4*)(w2f + elem))[1];
            *(bfrag*)(w2bf + elem) = cvt8(a, b);
        }
        return;
    }
    __shared__ alignas(16) short lds[65536];
    if (bid < MID_NDS) {
        constexpr int cpx = MID_NDS / 8;
        const int virt = (bid & 7) * cpx + (bid >> 3);
        const int n0 = (virt & 7) * 256, m0 = (virt >> 3) * 256;
        down_core<SHDIM, false>(act_sh, sw2bf, out, nullptr, 0, T_TOK, m0, n0, lds);
    } else {
        const int b = bid - MID_NDS;             // 256 % 8 == 0: b%8 still = XCD
        constexpr int cpx = MID_NUE / 8;
        const int virt = (b & 7) * cpx + (b >> 3);
        const int e = virt / 352, r = virt % 352;
        const int n0 = (r % 11) * 128, m0 = (r / 11) * 256;
        const int count = meta[e], base = meta[16 + e];
        if (m0 >= count) return;
        up_core<HDIM, true>(xbf, w1bf + (size_t)e * HDIM * DIM, w3bf + (size_t)e * HDIM * DIM,
                            act_ex, list, base, count, m0, n0, lds);
    }
}

// out[t] += s_e[e0]*y[slot0] + s_e[e1]*y[slot1]
__global__ __launch_bounds__(256) void combine_kernel(
    float* __restrict__ out, const __hip_bfloat16* __restrict__ yscr,
    const int* __restrict__ sel, const int2* __restrict__ slots,
    const float* __restrict__ s_e)
{
    const int t = blockIdx.x;
    const int d = threadIdx.x * 8;
    const int2 sl = slots[t];
    const float se0 = s_e[sel[2 * t]];
    const float se1 = s_e[sel[2 * t + 1]];
    bfrag y0 = *(const bfrag*)&yscr[(size_t)sl.x * DIM + d];
    bfrag y1 = *(const bfrag*)&yscr[(size_t)sl.y * DIM + d];
    float4* o = (float4*)(out + (size_t)t * DIM + d);
    float4 o0 = o[0], o1 = o[1];
    o0.x += se0 * bf2f(y0[0]) + se1 * bf2f(y1[0]);
    o0.y += se0 * bf2f(y0[1]) + se1 * bf2f(y1[1]);
    o0.z += se0 * bf2f(y0[2]) + se1 * bf2f(y1[2]);
    o0.w += se0 * bf2f(y0[3]) + se1 * bf2f(y1[3]);
    o1.x += se0 * bf2f(y0[4]) + se1 * bf2f(y1[4]);
    o1.y += se0 * bf2f(y0[5]) + se1 * bf2f(y1[5]);
    o1.z += se0 * bf2f(y0[6]) + se1 * bf2f(y1[6]);
    o1.w += se0 * bf2f(y0[7]) + se1 * bf2f(y1[7]);
    o[0] = o0; o[1] = o1;
}

extern "C" void kernel_launch(void* const* d_in, const int* in_sizes, int n_in,
                              void* d_out, int out_size, void* d_ws, size_t ws_size,
                              hipStream_t stream) {
    const float* x   = (const float*)d_in[0];
    const float* gw  = (const float*)d_in[1];
    const float* w1  = (const float*)d_in[2];
    const float* w3  = (const float*)d_in[3];
    const float* w2  = (const float*)d_in[4];
    const float* sw1 = (const float*)d_in[5];
    const float* sw3 = (const float*)d_in[6];
    const float* sw2 = (const float*)d_in[7];
    float* out = (float*)d_out;

    const size_t SZ_X    = (size_t)T_TOK * DIM * 2;           // 33.6 MB
    const size_t SZ_W    = (size_t)NEXP * HDIM * DIM * 2;     // 46.1 MB each
    const size_t SZ_SW   = (size_t)SHDIM * DIM * 2;           // 11.5 MB each
    const size_t SZ_ACTS = (size_t)T_TOK * SHDIM * 2;         // 46.1 MB
    const size_t SZ_ACTE = (size_t)2 * T_TOK * HDIM * 2;      // 46.1 MB
    const size_t SZ_INTS = (size_t)6 * T_TOK * sizeof(int) + 512;
    const size_t need_base   = SZ_X + 3 * SZ_W + 3 * SZ_SW + SZ_ACTS + SZ_INTS;
    const size_t need_merged = need_base + SZ_ACTE;           // ~299 MB (fit confirmed)

    char* p = (char*)d_ws;
    __hip_bfloat16* xbf   = (__hip_bfloat16*)p; p += SZ_X;
    __hip_bfloat16* w1bf  = (__hip_bfloat16*)p; p += SZ_W;
    __hip_bfloat16* w3bf  = (__hip_bfloat16*)p; p += SZ_W;
    __hip_bfloat16* w2bf  = (__hip_bfloat16*)p; p += SZ_W;
    __hip_bfloat16* sw1bf = (__hip_bfloat16*)p; p += SZ_SW;
    __hip_bfloat16* sw3bf = (__hip_bfloat16*)p; p += SZ_SW;
    __hip_bfloat16* sw2bf = (__hip_bfloat16*)p; p += SZ_SW;
    __hip_bfloat16* act_sh = (__hip_bfloat16*)p; p += SZ_ACTS;
    const bool merged = (need_merged <= ws_size);
    __hip_bfloat16* act_ex = merged ? (__hip_bfloat16*)p : act_sh;  // fallback aliases
    if (merged) p += SZ_ACTE;
    int*  list  = (int*)p;  p += (size_t)2 * T_TOK * sizeof(int);
    int*  sel   = (int*)p;  p += (size_t)2 * T_TOK * sizeof(int);
    int2* slots = (int2*)p; p += (size_t)2 * T_TOK * sizeof(int);
    int*  meta  = (int*)p;
    float* s_e  = (float*)(meta + 32);
    // yscr (64 MB) aliases xbf+w1bf (dead once the expert-up work finishes)
    __hip_bfloat16* yscr = (__hip_bfloat16*)d_ws;
    if (need_base > ws_size) return;

    hipMemsetAsync(meta, 0, 256, stream);
    gate_cvt_kernel<<<T_TOK / 32 + 256, 256, 0, stream>>>(
        x, gw, xbf, sel, meta, s_e, sw1, sw3, sw2, sw1bf, sw3bf, sw2bf);
    scan_kernel<<<1, 64, 0, stream>>>(meta);
    fill_kernel<<<T_TOK / 256, 256, 0, stream>>>(sel, meta, list, slots);

    upsh_cvt_k<<<UPSH_NG + UPSH_NCVT, 512, 0, stream>>>(
        xbf, sw1bf, sw3bf, act_sh, w1, w3, w1bf, w3bf);

    if (merged) {
        mid_merged<<<MID_NDS + MID_NUE + MID_NCVT, 512, 0, stream>>>(
            act_sh, sw2bf, out, xbf, w1bf, w3bf, act_ex, list, meta, w2, w2bf);
        down_k<HDIM, true><<<dim3(DIM / 256, T_TOK / 256, NEXP), 512, 0, stream>>>(
            act_ex, w2bf, out, yscr, meta);
    } else {
        cvt_w2_kernel<<<2048, 256, 0, stream>>>(w2, w2bf);
        down_k<SHDIM, false><<<dim3(DIM / 256, T_TOK / 256, 1), 512, 0, stream>>>(
            act_sh, sw2bf, out, nullptr, meta);
        up_k<HDIM, true><<<dim3(HDIM / 128, T_TOK / 256, NEXP), 512, 0, stream>>>(
            xbf, w1bf, w3bf, act_ex, list, meta);
        down_k<HDIM, true><<<dim3(DIM / 256, T_TOK / 256, NEXP), 512, 0, stream>>>(
            act_ex, w2bf, out, yscr, meta);
    }
    combine_kernel<<<T_TOK, 256, 0, stream>>>(out, yscr, sel, slots, s_e);
}